// Round 6
// baseline (1741.537 us; speedup 1.0000x reference)
//
#include <hip/hip_runtime.h>
#include <hip/hip_fp16.h>

#define N_NODES 50000
#define N_EDGES 800000
#define D_IN 128
#define D_HID 256
#define D_OUT 128
#define NB 782            // ceil(N_NODES / 64) buckets of 64 nodes
#define GEMM_GRID 512

typedef _Float16 f16x8 __attribute__((ext_vector_type(8)));
typedef float f32x4 __attribute__((ext_vector_type(4)));

// ---------------- degree + bucket offsets (no 50k scan, no csr_src) ----------

__global__ void zero_deg(int* __restrict__ deg) {
    int i = blockIdx.x * blockDim.x + threadIdx.x;
    if (i < N_NODES) deg[i] = 0;
}

__global__ void deg_kernel(const int* __restrict__ dst, int* __restrict__ deg) {
    int i = blockIdx.x * blockDim.x + threadIdx.x;
    if (i < N_EDGES) atomicAdd(&deg[dst[i]], 1);
}

// 782 blocks x 64 threads (1 wave): deg_inv + per-bucket degree sum.
__global__ __launch_bounds__(64)
void bucket_reduce(const int* __restrict__ deg, float* __restrict__ deg_inv,
                   int* __restrict__ bucket_cnt) {
    int b = blockIdx.x, t = threadIdx.x;
    int i = b * 64 + t;
    int d = (i < N_NODES) ? deg[i] : 0;
    if (i < N_NODES) deg_inv[i] = 1.0f / fmaxf((float)d, 1.0f);
    int s = d;
    #pragma unroll
    for (int off = 32; off > 0; off >>= 1) s += __shfl_down(s, off);
    if (t == 0) bucket_cnt[b] = s;
}

// 1 block x 1024: exclusive scan of 782 bucket counts -> offsets + cursors.
__global__ __launch_bounds__(1024)
void bucket_scan(const int* __restrict__ bucket_cnt, int* __restrict__ bucket_off,
                 int* __restrict__ bucket_cursor) {
    __shared__ int s[1024];
    int tid = threadIdx.x;
    int v = (tid < NB) ? bucket_cnt[tid] : 0;
    s[tid] = v;
    __syncthreads();
    for (int off = 1; off < 1024; off <<= 1) {
        int t = (tid >= off) ? s[tid - off] : 0;
        __syncthreads();
        s[tid] += t;
        __syncthreads();
    }
    if (tid < NB) {
        int e = s[tid] - v;       // exclusive
        bucket_off[tid] = e;
        bucket_cursor[tid] = e;
    }
    if (tid == 0) bucket_off[NB] = N_EDGES;
}

// One edge pass: scatter (src,dst) pairs into bucket-contiguous regions.
__global__ void partition_pairs(const int* __restrict__ src, const int* __restrict__ dst,
                                int* __restrict__ bucket_cursor, int2* __restrict__ pairs) {
    int e = blockIdx.x * blockDim.x + threadIdx.x;
    if (e < N_EDGES) {
        int d = dst[e];
        int p = atomicAdd(&bucket_cursor[d >> 6], 1);
        pairs[p] = make_int2(src[e], d);
    }
}

// ---------------- fp32 -> fp16 conversion ----------------

__global__ void cvt_half(const float* __restrict__ in, __half2* __restrict__ out, int n2) {
    int i = blockIdx.x * blockDim.x + threadIdx.x;
    if (i < n2) {
        float2 v = ((const float2*)in)[i];
        out[i] = __float22half2_rn(v);
    }
}

// 64 blocks x 256: all four 256x128-equivalent weight matrices in one launch.
__global__ void cvt_weights(const float* __restrict__ a, const float* __restrict__ b,
                            const float* __restrict__ c, const float* __restrict__ d,
                            __half2* __restrict__ oa, __half2* __restrict__ ob,
                            __half2* __restrict__ oc, __half2* __restrict__ od) {
    int i = blockIdx.x * 256 + threadIdx.x;   // 16384 half2 per matrix
    if (i < 16384) {
        oa[i] = __float22half2_rn(((const float2*)a)[i]);
        ob[i] = __float22half2_rn(((const float2*)b)[i]);
        oc[i] = __float22half2_rn(((const float2*)c)[i]);
        od[i] = __float22half2_rn(((const float2*)d)[i]);
    }
}

// ---------------- bucketed mean aggregation (LDS accumulate, no csr) ----------
// Block-per-bucket. acc[64 nodes][128 feats] fp32 in LDS (32 KB -> 4 blocks/CU).
// Wave w walks pairs[beg+w::4]; per edge: 256B feat row read + 2 ds_add_f32/lane
// (fixed node => 2-way bank aliasing, free per m136).

template<bool ACCUM>
__global__ __launch_bounds__(256)
void bucket_gather(const __half2* __restrict__ feat, const int2* __restrict__ pairs,
                   const int* __restrict__ bucket_off, const float* __restrict__ deg_inv,
                   __half2* __restrict__ outh, float* __restrict__ outf) {
    __shared__ float acc[64][128];
    const int tid = threadIdx.x;
    const int b = blockIdx.x;
    for (int i = tid; i < 64 * 128; i += 256) ((float*)acc)[i] = 0.f;
    __syncthreads();

    const int lane = tid & 63;
    const int wave = tid >> 6;
    const int beg = bucket_off[b];
    const int end = bucket_off[b + 1];
    int e = beg + wave;
    for (; e + 4 < end; e += 8) {             // 2 edges in flight per wave
        int2 p0 = pairs[e];
        int2 p1 = pairs[e + 4];
        float2 v0 = __half22float2(feat[(size_t)p0.x * 64 + lane]);
        float2 v1 = __half22float2(feat[(size_t)p1.x * 64 + lane]);
        int n0 = p0.y & 63;
        int n1 = p1.y & 63;
        atomicAdd(&acc[n0][2 * lane], v0.x);
        atomicAdd(&acc[n0][2 * lane + 1], v0.y);
        atomicAdd(&acc[n1][2 * lane], v1.x);
        atomicAdd(&acc[n1][2 * lane + 1], v1.y);
    }
    for (; e < end; e += 4) {
        int2 p0 = pairs[e];
        float2 v0 = __half22float2(feat[(size_t)p0.x * 64 + lane]);
        int n0 = p0.y & 63;
        atomicAdd(&acc[n0][2 * lane], v0.x);
        atomicAdd(&acc[n0][2 * lane + 1], v0.y);
    }
    __syncthreads();

    // epilogue: thread (node = tid>>2, quarter fq = tid&3) covers 32 feats.
    int node = tid >> 2, fq = tid & 3;
    int gnode = b * 64 + node;
    if (gnode < N_NODES) {
        float di = deg_inv[gnode];
        if (ACCUM) {
            float2* o = (float2*)(outf + (size_t)gnode * 128) + fq * 16;
            #pragma unroll
            for (int i = 0; i < 16; ++i) {
                float2 t = o[i];
                t.x += acc[node][fq * 32 + 2 * i] * di;
                t.y += acc[node][fq * 32 + 2 * i + 1] * di;
                o[i] = t;
            }
        } else {
            __half2* o = outh + (size_t)gnode * 64 + fq * 16;
            #pragma unroll
            for (int i = 0; i < 16; ++i)
                o[i] = __float22half2_rn(make_float2(
                    acc[node][fq * 32 + 2 * i] * di,
                    acc[node][fq * 32 + 2 * i + 1] * di));
        }
    }
}

// ---------------- MFMA fp16 GEMMs: B hoisted to registers, row-tile loop ------
// mfma_f32_16x16x32_f16 layouts (verified R4/R5):
//   A frag: lane holds A[m = lane&15][k = kc + (lane>>4)*8 + j]
//   B frag: lane holds W[n = lane&15][k = kc + (lane>>4)*8 + j]  (W row-major [J,K])
//   C/D:    col = lane&15 (n), row = (lane>>4)*4 + reg

__global__ __launch_bounds__(256, 2)
void gemm_l1(const __half* __restrict__ Aa, const __half* __restrict__ Ba,
             const __half* __restrict__ Ab, const __half* __restrict__ Bb,
             const float* __restrict__ bias, __half* __restrict__ H) {
    const int lane = threadIdx.x & 63;
    const int wave = threadIdx.x >> 6;      // owns cols [wave*64, wave*64+64)
    const int quad = lane >> 4;
    const int l16 = lane & 15;
    const int koff = quad * 8;

    f16x8 bf[2][4][4];                       // 128 VGPRs of B fragments
    #pragma unroll
    for (int p = 0; p < 2; ++p) {
        const __half* __restrict__ B = p ? Bb : Ba;
        #pragma unroll
        for (int kc = 0; kc < 4; ++kc)
            #pragma unroll
            for (int nt = 0; nt < 4; ++nt)
                bf[p][kc][nt] = *(const f16x8*)(
                    B + (size_t)(wave * 64 + nt * 16 + l16) * D_IN + kc * 32 + koff);
    }
    float bv[4];
    #pragma unroll
    for (int nt = 0; nt < 4; ++nt) bv[nt] = bias[wave * 64 + nt * 16 + l16];

    const int NT = N_NODES / 16;            // 3125 exact
    const int g = gridDim.x;

    auto loadA = [&](int t, f16x8 (&a)[2][4]) {
        const size_t arow = (size_t)(t * 16 + l16) * D_IN + koff;
        #pragma unroll
        for (int kc = 0; kc < 4; ++kc) {
            a[0][kc] = *(const f16x8*)(Aa + arow + kc * 32);
            a[1][kc] = *(const f16x8*)(Ab + arow + kc * 32);
        }
    };
    auto step = [&](int tile, const f16x8 (&a)[2][4]) {
        f32x4 acc[4] = {};
        #pragma unroll
        for (int p = 0; p < 2; ++p)
            #pragma unroll
            for (int kc = 0; kc < 4; ++kc)
                #pragma unroll
                for (int nt = 0; nt < 4; ++nt)
                    acc[nt] = __builtin_amdgcn_mfma_f32_16x16x32_f16(
                        a[p][kc], bf[p][kc][nt], acc[nt], 0, 0, 0);
        #pragma unroll
        for (int nt = 0; nt < 4; ++nt) {
            int col = wave * 64 + nt * 16 + l16;
            #pragma unroll
            for (int r = 0; r < 4; ++r) {
                int row = tile * 16 + quad * 4 + r;
                H[(size_t)row * D_HID + col] =
                    __float2half(fmaxf(acc[nt][r] + bv[nt], 0.f));
            }
        }
    };

    f16x8 A0[2][4], A1[2][4];
    int tile = blockIdx.x;
    loadA(tile, A0);
    while (true) {
        if (tile + g < NT) loadA(tile + g, A1);
        step(tile, A0);
        tile += g;
        if (tile >= NT) break;
        if (tile + g < NT) loadA(tile + g, A0);
        step(tile, A1);
        tile += g;
        if (tile >= NT) break;
    }
}

__global__ __launch_bounds__(256, 2)
void gemm_l2(const __half* __restrict__ Hh, const __half* __restrict__ B0,
             const __half* __restrict__ B1, const float* __restrict__ bias,
             __half* __restrict__ P, float* __restrict__ out) {
    const int lane = threadIdx.x & 63;
    const int wave = threadIdx.x >> 6;      // owns cols [wave*32, wave*32+32)
    const int quad = lane >> 4;
    const int l16 = lane & 15;
    const int koff = quad * 8;

    f16x8 bf0[8][2], bf1[8][2];             // 128 VGPRs of B fragments
    #pragma unroll
    for (int kc = 0; kc < 8; ++kc)
        #pragma unroll
        for (int nt = 0; nt < 2; ++nt) {
            size_t brow = (size_t)(wave * 32 + nt * 16 + l16) * D_HID + kc * 32 + koff;
            bf0[kc][nt] = *(const f16x8*)(B0 + brow);
            bf1[kc][nt] = *(const f16x8*)(B1 + brow);
        }
    float bv[2];
    #pragma unroll
    for (int nt = 0; nt < 2; ++nt) bv[nt] = bias[wave * 32 + nt * 16 + l16];

    const int NT = N_NODES / 16;
    const int g = gridDim.x;

    auto loadA = [&](int t, f16x8 (&a)[8]) {
        const size_t arow = (size_t)(t * 16 + l16) * D_HID + koff;
        #pragma unroll
        for (int kc = 0; kc < 8; ++kc)
            a[kc] = *(const f16x8*)(Hh + arow + kc * 32);
    };
    auto step = [&](int tile, const f16x8 (&a)[8]) {
        f32x4 acc0[2] = {};
        f32x4 acc1[2] = {};
        #pragma unroll
        for (int kc = 0; kc < 8; ++kc)
            #pragma unroll
            for (int nt = 0; nt < 2; ++nt) {
                acc0[nt] = __builtin_amdgcn_mfma_f32_16x16x32_f16(
                    a[kc], bf0[kc][nt], acc0[nt], 0, 0, 0);
                acc1[nt] = __builtin_amdgcn_mfma_f32_16x16x32_f16(
                    a[kc], bf1[kc][nt], acc1[nt], 0, 0, 0);
            }
        #pragma unroll
        for (int nt = 0; nt < 2; ++nt) {
            int col = wave * 32 + nt * 16 + l16;
            #pragma unroll
            for (int r = 0; r < 4; ++r) {
                int row = tile * 16 + quad * 4 + r;
                P[(size_t)row * D_OUT + col] = __float2half(acc0[nt][r]);
                out[(size_t)row * D_OUT + col] = acc1[nt][r] + bv[nt];
            }
        }
    };

    f16x8 A0[8], A1[8];
    int tile = blockIdx.x;
    loadA(tile, A0);
    while (true) {
        if (tile + g < NT) loadA(tile + g, A1);
        step(tile, A0);
        tile += g;
        if (tile >= NT) break;
        if (tile + g < NT) loadA(tile + g, A0);
        step(tile, A1);
        tile += g;
        if (tile >= NT) break;
    }
}

extern "C" void kernel_launch(void* const* d_in, const int* in_sizes, int n_in,
                              void* d_out, int out_size, void* d_ws, size_t ws_size,
                              hipStream_t stream) {
    const float* x   = (const float*)d_in[0];
    const float* Wl1 = (const float*)d_in[1];
    const float* bl1 = (const float*)d_in[2];
    const float* Wr1 = (const float*)d_in[3];
    const float* Wl2 = (const float*)d_in[4];
    const float* bl2 = (const float*)d_in[5];
    const float* Wr2 = (const float*)d_in[6];
    const int*   ei  = (const int*)d_in[7];
    const int* src = ei;              // edge_index[0]
    const int* dst = ei + N_EDGES;    // edge_index[1]
    float* out = (float*)d_out;

    // Workspace layout, 256B-aligned slabs (~71 MB; ws >= 128 MB per R1)
    char* w = (char*)d_ws;
    auto alloc = [&](size_t bytes) {
        char* r = w;
        w += (bytes + 255) & ~(size_t)255;
        return r;
    };
    int*     deg       = (int*)alloc((size_t)N_NODES * 4);
    float*   deg_inv   = (float*)alloc((size_t)N_NODES * 4);
    int*     bcnt      = (int*)alloc(NB * 4);
    int*     boff      = (int*)alloc((NB + 1) * 4);
    int*     bcur      = (int*)alloc(NB * 4);
    int2*    pairs     = (int2*)alloc((size_t)N_EDGES * 8);
    __half2* xb        = (__half2*)alloc((size_t)N_NODES * 64 * 4);   // x fp16
    __half2* mean1     = (__half2*)alloc((size_t)N_NODES * 64 * 4);   // mean(x) fp16
    __half*  h         = (__half*)alloc((size_t)N_NODES * 256 * 2);   // layer-1 out
    __half2* pb        = (__half2*)alloc((size_t)N_NODES * 64 * 4);   // h@Wl2^T fp16
    __half*  wl1h      = (__half*)alloc(4 * 32768 * 2);
    __half*  wr1h = wl1h + 32768;
    __half*  wl2h = wr1h + 32768;
    __half*  wr2h = wl2h + 32768;

    // degree -> bucket offsets -> bucketed edge partition
    zero_deg<<<(N_NODES + 255) / 256, 256, 0, stream>>>(deg);
    deg_kernel<<<(N_EDGES + 255) / 256, 256, 0, stream>>>(dst, deg);
    bucket_reduce<<<NB, 64, 0, stream>>>(deg, deg_inv, bcnt);
    bucket_scan<<<1, 1024, 0, stream>>>(bcnt, boff, bcur);
    partition_pairs<<<(N_EDGES + 255) / 256, 256, 0, stream>>>(src, dst, bcur, pairs);

    // fp16 conversions
    cvt_half<<<12500, 256, 0, stream>>>(x, xb, N_NODES * 64);
    cvt_weights<<<64, 256, 0, stream>>>(Wl1, Wr1, Wl2, Wr2,
        (__half2*)wl1h, (__half2*)wr1h, (__half2*)wl2h, (__half2*)wr2h);

    // Layer 1: h = relu(mean(x) @ Wl1^T + x @ Wr1^T + bl1)
    bucket_gather<false><<<NB, 256, 0, stream>>>(xb, pairs, boff, deg_inv, mean1, nullptr);
    gemm_l1<<<GEMM_GRID, 256, 0, stream>>>(
        (const __half*)mean1, wl1h, (const __half*)xb, wr1h, bl1, h);

    // Layer 2 (reordered): p = h @ Wl2^T; out = h @ Wr2^T + bl2; out += mean(p)
    gemm_l2<<<GEMM_GRID, 256, 0, stream>>>(
        h, wl2h, wr2h, bl2, (__half*)pb, out);
    bucket_gather<true><<<NB, 256, 0, stream>>>(pb, pairs, boff, deg_inv, nullptr, out);
}

// Round 7
// 459.990 us; speedup vs baseline: 3.7860x; 3.7860x over previous
//
#include <hip/hip_runtime.h>
#include <hip/hip_fp16.h>

#define N_NODES 50000
#define N_EDGES 800000
#define D_IN 128
#define D_HID 256
#define D_OUT 128
#define NCHUNK 196   // ceil(N_NODES / 256)
#define NB 782       // ceil(N_NODES / 64) buckets of 64 consecutive nodes
#define GEMM_GRID 512

typedef _Float16 f16x8 __attribute__((ext_vector_type(8)));
typedef float f32x4 __attribute__((ext_vector_type(4)));

// ---------------- CSR build ----------------

__global__ void zero_deg(int* __restrict__ deg) {
    int i = blockIdx.x * blockDim.x + threadIdx.x;
    if (i < N_NODES) deg[i] = 0;
}

__global__ void deg_kernel(const int* __restrict__ dst, int* __restrict__ deg) {
    int i = blockIdx.x * blockDim.x + threadIdx.x;
    if (i < N_EDGES) atomicAdd(&deg[dst[i]], 1);
}

__global__ void chunk_sum(const int* __restrict__ deg, int* __restrict__ partial) {
    __shared__ int s[256];
    int i = blockIdx.x * 256 + threadIdx.x;
    s[threadIdx.x] = (i < N_NODES) ? deg[i] : 0;
    __syncthreads();
    for (int off = 128; off > 0; off >>= 1) {
        if (threadIdx.x < off) s[threadIdx.x] += s[threadIdx.x + off];
        __syncthreads();
    }
    if (threadIdx.x == 0) partial[blockIdx.x] = s[0];
}

__global__ void chunk_scan(const int* __restrict__ partial, int* __restrict__ chunkOff) {
    __shared__ int s[256];
    int tid = threadIdx.x;
    int v = (tid < NCHUNK) ? partial[tid] : 0;
    s[tid] = v;
    __syncthreads();
    for (int off = 1; off < 256; off <<= 1) {
        int t = (tid >= off) ? s[tid - off] : 0;
        __syncthreads();
        s[tid] += t;
        __syncthreads();
    }
    if (tid < NCHUNK) chunkOff[tid] = s[tid] - v;   // exclusive
}

// Also emits per-64-node-bucket cursor bases (bcur[b] = row_ptr[64b]).
__global__ void scatter_scan(const int* __restrict__ deg, const int* __restrict__ chunkOff,
                             int* __restrict__ row_ptr, int* __restrict__ bcur,
                             float* __restrict__ deg_inv) {
    __shared__ int s[256];
    int tid = threadIdx.x;
    int i = blockIdx.x * 256 + tid;
    int v = (i < N_NODES) ? deg[i] : 0;
    s[tid] = v;
    __syncthreads();
    for (int off = 1; off < 256; off <<= 1) {
        int t = (tid >= off) ? s[tid - off] : 0;
        __syncthreads();
        s[tid] += t;
        __syncthreads();
    }
    if (i < N_NODES) {
        int rp = chunkOff[blockIdx.x] + s[tid] - v;   // exclusive scan value
        row_ptr[i] = rp;
        if ((i & 63) == 0) bcur[i >> 6] = rp;         // bucket cursor base
        deg_inv[i] = 1.0f / fmaxf((float)v, 1.0f);
        if (i == N_NODES - 1) row_ptr[N_NODES] = N_EDGES;
    }
}

// Phase A: append (src,dst) into bucket-contiguous regions (782 dense streams).
__global__ void partition_pairs(const int* __restrict__ src, const int* __restrict__ dst,
                                int* __restrict__ bcur, int2* __restrict__ pairs) {
    int e = blockIdx.x * blockDim.x + threadIdx.x;
    if (e < N_EDGES) {
        int d = dst[e];
        int p = atomicAdd(&bcur[d >> 6], 1);
        pairs[p] = make_int2(src[e], d);
    }
}

// Phase B: block-per-bucket; sort bucket's pairs into per-node CSR order via
// LDS stage, then write csr_src slice coalesced. Result = exact global CSR.
__global__ __launch_bounds__(256)
void csr_sort(const int2* __restrict__ pairs, const int* __restrict__ row_ptr,
              int* __restrict__ csr_src) {
    __shared__ int stage[2048];
    __shared__ int curs[64];
    const int b = blockIdx.x;
    const int tid = threadIdx.x;
    const int nodebase = b * 64;
    const int base = row_ptr[nodebase];
    int endn = nodebase + 64;
    if (endn > N_NODES) endn = N_NODES;
    const int cnt = row_ptr[endn] - base;
    if (tid < 64) {
        int gn = nodebase + tid;
        curs[tid] = ((gn < N_NODES) ? row_ptr[gn] : N_EDGES) - base;  // relative
    }
    __syncthreads();
    if (cnt <= 2048) {
        for (int i = tid; i < cnt; i += 256) {
            int2 p = pairs[base + i];
            int pos = atomicAdd(&curs[p.y & 63], 1);
            stage[pos] = p.x;
        }
        __syncthreads();
        for (int i = tid; i < cnt; i += 256)
            csr_src[base + i] = stage[i];
    } else {  // safety fallback (never expected at ~1024 edges/bucket)
        for (int i = tid; i < cnt; i += 256) {
            int2 p = pairs[base + i];
            int pos = atomicAdd(&curs[p.y & 63], 1);
            csr_src[base + pos] = p.x;
        }
    }
}

// ---------------- fp32 -> fp16 conversion ----------------

__global__ void cvt_half(const float* __restrict__ in, __half2* __restrict__ out, int n2) {
    int i = blockIdx.x * blockDim.x + threadIdx.x;
    if (i < n2) {
        float2 v = ((const float2*)in)[i];
        out[i] = __float22half2_rn(v);
    }
}

__global__ void cvt_weights(const float* __restrict__ a, const float* __restrict__ b,
                            const float* __restrict__ c, const float* __restrict__ d,
                            __half2* __restrict__ oa, __half2* __restrict__ ob,
                            __half2* __restrict__ oc, __half2* __restrict__ od) {
    int i = blockIdx.x * 256 + threadIdx.x;   // 16384 half2 per matrix
    if (i < 16384) {
        oa[i] = __float22half2_rn(((const float2*)a)[i]);
        ob[i] = __float22half2_rn(((const float2*)b)[i]);
        oc[i] = __float22half2_rn(((const float2*)c)[i]);
        od[i] = __float22half2_rn(((const float2*)d)[i]);
    }
}

// ---------------- mean aggregation (CSR gather, wave-per-node, fp16 rows) -----

__global__ __launch_bounds__(256)
void gather_mean_h(const __half2* __restrict__ feat, const int* __restrict__ row_ptr,
                   const int* __restrict__ csr_src, const float* __restrict__ deg_inv,
                   __half2* __restrict__ outv) {
    const int lane = threadIdx.x & 63;
    const int n = blockIdx.x * 4 + (threadIdx.x >> 6);   // grid exactly covers N_NODES
    const int beg = row_ptr[n];
    const int end = row_ptr[n + 1];
    float a0 = 0.f, a1 = 0.f;
    int e = beg;
    for (; e + 4 <= end; e += 4) {
        int s0 = csr_src[e + 0];
        int s1 = csr_src[e + 1];
        int s2 = csr_src[e + 2];
        int s3 = csr_src[e + 3];
        float2 v0 = __half22float2(feat[s0 * 64 + lane]);
        float2 v1 = __half22float2(feat[s1 * 64 + lane]);
        float2 v2 = __half22float2(feat[s2 * 64 + lane]);
        float2 v3 = __half22float2(feat[s3 * 64 + lane]);
        a0 += (v0.x + v1.x) + (v2.x + v3.x);
        a1 += (v0.y + v1.y) + (v2.y + v3.y);
    }
    for (; e < end; ++e) {
        float2 v = __half22float2(feat[csr_src[e] * 64 + lane]);
        a0 += v.x;
        a1 += v.y;
    }
    float di = deg_inv[n];
    outv[n * 64 + lane] = __float22half2_rn(make_float2(a0 * di, a1 * di));
}

__global__ __launch_bounds__(256)
void gather_mean_add_f32(const __half2* __restrict__ feat, const int* __restrict__ row_ptr,
                         const int* __restrict__ csr_src, const float* __restrict__ deg_inv,
                         float* __restrict__ out) {
    const int lane = threadIdx.x & 63;
    const int n = blockIdx.x * 4 + (threadIdx.x >> 6);
    const int beg = row_ptr[n];
    const int end = row_ptr[n + 1];
    float a0 = 0.f, a1 = 0.f;
    int e = beg;
    for (; e + 4 <= end; e += 4) {
        int s0 = csr_src[e + 0];
        int s1 = csr_src[e + 1];
        int s2 = csr_src[e + 2];
        int s3 = csr_src[e + 3];
        float2 v0 = __half22float2(feat[s0 * 64 + lane]);
        float2 v1 = __half22float2(feat[s1 * 64 + lane]);
        float2 v2 = __half22float2(feat[s2 * 64 + lane]);
        float2 v3 = __half22float2(feat[s3 * 64 + lane]);
        a0 += (v0.x + v1.x) + (v2.x + v3.x);
        a1 += (v0.y + v1.y) + (v2.y + v3.y);
    }
    for (; e < end; ++e) {
        float2 v = __half22float2(feat[csr_src[e] * 64 + lane]);
        a0 += v.x;
        a1 += v.y;
    }
    float di = deg_inv[n];
    float2* o = (float2*)(out + (size_t)n * 128) + lane;
    float2 v = *o;
    v.x += a0 * di;
    v.y += a1 * di;
    *o = v;
}

// ---------------- MFMA fp16 GEMMs: B hoisted to registers, row-tile loop ------
// mfma_f32_16x16x32_f16 layouts (verified R4/R5):
//   A frag: lane holds A[m = lane&15][k = kc + (lane>>4)*8 + j]
//   B frag: lane holds W[n = lane&15][k = kc + (lane>>4)*8 + j]  (W row-major [J,K])
//   C/D:    col = lane&15 (n), row = (lane>>4)*4 + reg

__global__ __launch_bounds__(256, 2)
void gemm_l1(const __half* __restrict__ Aa, const __half* __restrict__ Ba,
             const __half* __restrict__ Ab, const __half* __restrict__ Bb,
             const float* __restrict__ bias, __half* __restrict__ H) {
    const int lane = threadIdx.x & 63;
    const int wave = threadIdx.x >> 6;      // owns cols [wave*64, wave*64+64)
    const int quad = lane >> 4;
    const int l16 = lane & 15;
    const int koff = quad * 8;

    f16x8 bf[2][4][4];                       // 128 VGPRs of B fragments
    #pragma unroll
    for (int p = 0; p < 2; ++p) {
        const __half* __restrict__ B = p ? Bb : Ba;
        #pragma unroll
        for (int kc = 0; kc < 4; ++kc)
            #pragma unroll
            for (int nt = 0; nt < 4; ++nt)
                bf[p][kc][nt] = *(const f16x8*)(
                    B + (size_t)(wave * 64 + nt * 16 + l16) * D_IN + kc * 32 + koff);
    }
    float bv[4];
    #pragma unroll
    for (int nt = 0; nt < 4; ++nt) bv[nt] = bias[wave * 64 + nt * 16 + l16];

    const int NT = N_NODES / 16;            // 3125 exact
    const int g = gridDim.x;

    auto loadA = [&](int t, f16x8 (&a)[2][4]) {
        const size_t arow = (size_t)(t * 16 + l16) * D_IN + koff;
        #pragma unroll
        for (int kc = 0; kc < 4; ++kc) {
            a[0][kc] = *(const f16x8*)(Aa + arow + kc * 32);
            a[1][kc] = *(const f16x8*)(Ab + arow + kc * 32);
        }
    };
    auto step = [&](int tile, const f16x8 (&a)[2][4]) {
        f32x4 acc[4] = {};
        #pragma unroll
        for (int p = 0; p < 2; ++p)
            #pragma unroll
            for (int kc = 0; kc < 4; ++kc)
                #pragma unroll
                for (int nt = 0; nt < 4; ++nt)
                    acc[nt] = __builtin_amdgcn_mfma_f32_16x16x32_f16(
                        a[p][kc], bf[p][kc][nt], acc[nt], 0, 0, 0);
        #pragma unroll
        for (int nt = 0; nt < 4; ++nt) {
            int col = wave * 64 + nt * 16 + l16;
            #pragma unroll
            for (int r = 0; r < 4; ++r) {
                int row = tile * 16 + quad * 4 + r;
                H[(size_t)row * D_HID + col] =
                    __float2half(fmaxf(acc[nt][r] + bv[nt], 0.f));
            }
        }
    };

    f16x8 A0[2][4], A1[2][4];
    int tile = blockIdx.x;
    loadA(tile, A0);
    while (true) {
        if (tile + g < NT) loadA(tile + g, A1);
        step(tile, A0);
        tile += g;
        if (tile >= NT) break;
        if (tile + g < NT) loadA(tile + g, A0);
        step(tile, A1);
        tile += g;
        if (tile >= NT) break;
    }
}

__global__ __launch_bounds__(256, 2)
void gemm_l2(const __half* __restrict__ Hh, const __half* __restrict__ B0,
             const __half* __restrict__ B1, const float* __restrict__ bias,
             __half* __restrict__ P, float* __restrict__ out) {
    const int lane = threadIdx.x & 63;
    const int wave = threadIdx.x >> 6;      // owns cols [wave*32, wave*32+32)
    const int quad = lane >> 4;
    const int l16 = lane & 15;
    const int koff = quad * 8;

    f16x8 bf0[8][2], bf1[8][2];             // 128 VGPRs of B fragments
    #pragma unroll
    for (int kc = 0; kc < 8; ++kc)
        #pragma unroll
        for (int nt = 0; nt < 2; ++nt) {
            size_t brow = (size_t)(wave * 32 + nt * 16 + l16) * D_HID + kc * 32 + koff;
            bf0[kc][nt] = *(const f16x8*)(B0 + brow);
            bf1[kc][nt] = *(const f16x8*)(B1 + brow);
        }
    float bv[2];
    #pragma unroll
    for (int nt = 0; nt < 2; ++nt) bv[nt] = bias[wave * 32 + nt * 16 + l16];

    const int NT = N_NODES / 16;
    const int g = gridDim.x;

    auto loadA = [&](int t, f16x8 (&a)[8]) {
        const size_t arow = (size_t)(t * 16 + l16) * D_HID + koff;
        #pragma unroll
        for (int kc = 0; kc < 8; ++kc)
            a[kc] = *(const f16x8*)(Hh + arow + kc * 32);
    };
    auto step = [&](int tile, const f16x8 (&a)[8]) {
        f32x4 acc0[2] = {};
        f32x4 acc1[2] = {};
        #pragma unroll
        for (int kc = 0; kc < 8; ++kc)
            #pragma unroll
            for (int nt = 0; nt < 2; ++nt) {
                acc0[nt] = __builtin_amdgcn_mfma_f32_16x16x32_f16(
                    a[kc], bf0[kc][nt], acc0[nt], 0, 0, 0);
                acc1[nt] = __builtin_amdgcn_mfma_f32_16x16x32_f16(
                    a[kc], bf1[kc][nt], acc1[nt], 0, 0, 0);
            }
        #pragma unroll
        for (int nt = 0; nt < 2; ++nt) {
            int col = wave * 32 + nt * 16 + l16;
            #pragma unroll
            for (int r = 0; r < 4; ++r) {
                int row = tile * 16 + quad * 4 + r;
                P[(size_t)row * D_OUT + col] = __float2half(acc0[nt][r]);
                out[(size_t)row * D_OUT + col] = acc1[nt][r] + bv[nt];
            }
        }
    };

    f16x8 A0[8], A1[8];
    int tile = blockIdx.x;
    loadA(tile, A0);
    while (true) {
        if (tile + g < NT) loadA(tile + g, A1);
        step(tile, A0);
        tile += g;
        if (tile >= NT) break;
        if (tile + g < NT) loadA(tile + g, A0);
        step(tile, A1);
        tile += g;
        if (tile >= NT) break;
    }
}

extern "C" void kernel_launch(void* const* d_in, const int* in_sizes, int n_in,
                              void* d_out, int out_size, void* d_ws, size_t ws_size,
                              hipStream_t stream) {
    const float* x   = (const float*)d_in[0];
    const float* Wl1 = (const float*)d_in[1];
    const float* bl1 = (const float*)d_in[2];
    const float* Wr1 = (const float*)d_in[3];
    const float* Wl2 = (const float*)d_in[4];
    const float* bl2 = (const float*)d_in[5];
    const float* Wr2 = (const float*)d_in[6];
    const int*   ei  = (const int*)d_in[7];
    const int* src = ei;              // edge_index[0]
    const int* dst = ei + N_EDGES;    // edge_index[1]
    float* out = (float*)d_out;

    // Workspace layout, 256B-aligned slabs (~75 MB)
    char* w = (char*)d_ws;
    auto alloc = [&](size_t bytes) {
        char* r = w;
        w += (bytes + 255) & ~(size_t)255;
        return r;
    };
    int*     deg       = (int*)alloc((size_t)N_NODES * 4);
    int*     row_ptr   = (int*)alloc((size_t)(N_NODES + 1) * 4);
    int*     partial   = (int*)alloc(NCHUNK * 4);
    int*     chunkOff  = (int*)alloc(NCHUNK * 4);
    int*     bcur      = (int*)alloc(NB * 4);
    int2*    pairs     = (int2*)alloc((size_t)N_EDGES * 8);
    int*     csr_src   = (int*)alloc((size_t)N_EDGES * 4);
    float*   deg_inv   = (float*)alloc((size_t)N_NODES * 4);
    __half2* xb        = (__half2*)alloc((size_t)N_NODES * 64 * 4);   // x fp16
    __half2* mean1     = (__half2*)alloc((size_t)N_NODES * 64 * 4);   // mean(x) fp16
    __half*  h         = (__half*)alloc((size_t)N_NODES * 256 * 2);   // layer-1 out
    __half2* pb        = (__half2*)alloc((size_t)N_NODES * 64 * 4);   // h@Wl2^T fp16
    __half*  wl1h      = (__half*)alloc(4 * 32768 * 2);
    __half*  wr1h = wl1h + 32768;
    __half*  wl2h = wr1h + 32768;
    __half*  wr2h = wl2h + 32768;

    // CSR build: deg -> scan (row_ptr + bucket cursors) -> partition -> sort
    zero_deg<<<(N_NODES + 255) / 256, 256, 0, stream>>>(deg);
    deg_kernel<<<(N_EDGES + 255) / 256, 256, 0, stream>>>(dst, deg);
    chunk_sum<<<NCHUNK, 256, 0, stream>>>(deg, partial);
    chunk_scan<<<1, 256, 0, stream>>>(partial, chunkOff);
    scatter_scan<<<NCHUNK, 256, 0, stream>>>(deg, chunkOff, row_ptr, bcur, deg_inv);
    partition_pairs<<<(N_EDGES + 255) / 256, 256, 0, stream>>>(src, dst, bcur, pairs);
    csr_sort<<<NB, 256, 0, stream>>>(pairs, row_ptr, csr_src);

    // fp16 conversions
    cvt_half<<<12500, 256, 0, stream>>>(x, xb, N_NODES * 64);
    cvt_weights<<<64, 256, 0, stream>>>(Wl1, Wr1, Wl2, Wr2,
        (__half2*)wl1h, (__half2*)wr1h, (__half2*)wl2h, (__half2*)wr2h);

    // Layer 1: h = relu(mean(x) @ Wl1^T + x @ Wr1^T + bl1)
    gather_mean_h<<<12500, 256, 0, stream>>>(xb, row_ptr, csr_src, deg_inv, mean1);
    gemm_l1<<<GEMM_GRID, 256, 0, stream>>>(
        (const __half*)mean1, wl1h, (const __half*)xb, wr1h, bl1, h);

    // Layer 2 (reordered): p = h @ Wl2^T; out = h @ Wr2^T + bl2; out += mean(p)
    gemm_l2<<<GEMM_GRID, 256, 0, stream>>>(
        h, wl2h, wr2h, bl2, (__half*)pb, out);
    gather_mean_add_f32<<<12500, 256, 0, stream>>>(pb, row_ptr, csr_src, deg_inv, out);
}

// Round 8
// 295.448 us; speedup vs baseline: 5.8946x; 1.5569x over previous
//
#include <hip/hip_runtime.h>
#include <hip/hip_fp16.h>

#define N_NODES 50000
#define N_EDGES 800000
#define D_IN 128
#define D_HID 256
#define D_OUT 128
#define NCHUNK 196   // ceil(N_NODES / 256)
#define GEMM_GRID 512

typedef _Float16 f16x8 __attribute__((ext_vector_type(8)));
typedef float f32x4 __attribute__((ext_vector_type(4)));

// ---------------- CSR build (R5-proven: per-node cursors, 16 hits each) -------

__global__ void zero_deg(int* __restrict__ deg) {
    int i = blockIdx.x * blockDim.x + threadIdx.x;
    if (i < N_NODES) deg[i] = 0;
}

__global__ void deg_kernel(const int* __restrict__ dst, int* __restrict__ deg) {
    int i = blockIdx.x * blockDim.x + threadIdx.x;
    if (i < N_EDGES) atomicAdd(&deg[dst[i]], 1);
}

__global__ void chunk_sum(const int* __restrict__ deg, int* __restrict__ partial) {
    __shared__ int s[256];
    int i = blockIdx.x * 256 + threadIdx.x;
    s[threadIdx.x] = (i < N_NODES) ? deg[i] : 0;
    __syncthreads();
    for (int off = 128; off > 0; off >>= 1) {
        if (threadIdx.x < off) s[threadIdx.x] += s[threadIdx.x + off];
        __syncthreads();
    }
    if (threadIdx.x == 0) partial[blockIdx.x] = s[0];
}

__global__ void chunk_scan(const int* __restrict__ partial, int* __restrict__ chunkOff) {
    __shared__ int s[256];
    int tid = threadIdx.x;
    int v = (tid < NCHUNK) ? partial[tid] : 0;
    s[tid] = v;
    __syncthreads();
    for (int off = 1; off < 256; off <<= 1) {
        int t = (tid >= off) ? s[tid - off] : 0;
        __syncthreads();
        s[tid] += t;
        __syncthreads();
    }
    if (tid < NCHUNK) chunkOff[tid] = s[tid] - v;   // exclusive
}

__global__ void scatter_scan(const int* __restrict__ deg, const int* __restrict__ chunkOff,
                             int* __restrict__ row_ptr, int* __restrict__ cursor,
                             float* __restrict__ deg_inv) {
    __shared__ int s[256];
    int tid = threadIdx.x;
    int i = blockIdx.x * 256 + tid;
    int v = (i < N_NODES) ? deg[i] : 0;
    s[tid] = v;
    __syncthreads();
    for (int off = 1; off < 256; off <<= 1) {
        int t = (tid >= off) ? s[tid - off] : 0;
        __syncthreads();
        s[tid] += t;
        __syncthreads();
    }
    if (i < N_NODES) {
        int rp = chunkOff[blockIdx.x] + s[tid] - v;   // exclusive scan value
        row_ptr[i] = rp;
        cursor[i] = rp;
        deg_inv[i] = 1.0f / fmaxf((float)v, 1.0f);
        if (i == N_NODES - 1) row_ptr[N_NODES] = N_EDGES;
    }
}

__global__ void fill_csr(const int* __restrict__ src, const int* __restrict__ dst,
                         int* __restrict__ cursor, int* __restrict__ csr_src) {
    int e = blockIdx.x * blockDim.x + threadIdx.x;
    if (e < N_EDGES) {
        int p = atomicAdd(&cursor[dst[e]], 1);
        csr_src[p] = src[e];
    }
}

// ---------------- fp32 -> fp16 conversion ----------------

__global__ void cvt_half(const float* __restrict__ in, __half2* __restrict__ out, int n2) {
    int i = blockIdx.x * blockDim.x + threadIdx.x;
    if (i < n2) {
        float2 v = ((const float2*)in)[i];
        out[i] = __float22half2_rn(v);
    }
}

__global__ void cvt_weights(const float* __restrict__ a, const float* __restrict__ b,
                            const float* __restrict__ c, const float* __restrict__ d,
                            __half2* __restrict__ oa, __half2* __restrict__ ob,
                            __half2* __restrict__ oc, __half2* __restrict__ od) {
    int i = blockIdx.x * 256 + threadIdx.x;   // 16384 half2 per matrix
    if (i < 16384) {
        oa[i] = __float22half2_rn(((const float2*)a)[i]);
        ob[i] = __float22half2_rn(((const float2*)b)[i]);
        oc[i] = __float22half2_rn(((const float2*)c)[i]);
        od[i] = __float22half2_rn(((const float2*)d)[i]);
    }
}

// ---------------- mean aggregation (CSR gather, wave-per-node, ILP-8) ---------

__global__ __launch_bounds__(256)
void gather_mean_h(const __half2* __restrict__ feat, const int* __restrict__ row_ptr,
                   const int* __restrict__ csr_src, const float* __restrict__ deg_inv,
                   __half2* __restrict__ outv) {
    const int lane = threadIdx.x & 63;
    const int n = blockIdx.x * 4 + (threadIdx.x >> 6);   // grid exactly covers N_NODES
    const int beg = row_ptr[n];
    const int end = row_ptr[n + 1];
    float a0 = 0.f, a1 = 0.f;
    int e = beg;
    for (; e + 8 <= end; e += 8) {          // 8 independent row loads in flight
        int s0 = csr_src[e + 0], s1 = csr_src[e + 1];
        int s2 = csr_src[e + 2], s3 = csr_src[e + 3];
        int s4 = csr_src[e + 4], s5 = csr_src[e + 5];
        int s6 = csr_src[e + 6], s7 = csr_src[e + 7];
        float2 v0 = __half22float2(feat[s0 * 64 + lane]);
        float2 v1 = __half22float2(feat[s1 * 64 + lane]);
        float2 v2 = __half22float2(feat[s2 * 64 + lane]);
        float2 v3 = __half22float2(feat[s3 * 64 + lane]);
        float2 v4 = __half22float2(feat[s4 * 64 + lane]);
        float2 v5 = __half22float2(feat[s5 * 64 + lane]);
        float2 v6 = __half22float2(feat[s6 * 64 + lane]);
        float2 v7 = __half22float2(feat[s7 * 64 + lane]);
        a0 += ((v0.x + v1.x) + (v2.x + v3.x)) + ((v4.x + v5.x) + (v6.x + v7.x));
        a1 += ((v0.y + v1.y) + (v2.y + v3.y)) + ((v4.y + v5.y) + (v6.y + v7.y));
    }
    for (; e + 4 <= end; e += 4) {
        int s0 = csr_src[e + 0], s1 = csr_src[e + 1];
        int s2 = csr_src[e + 2], s3 = csr_src[e + 3];
        float2 v0 = __half22float2(feat[s0 * 64 + lane]);
        float2 v1 = __half22float2(feat[s1 * 64 + lane]);
        float2 v2 = __half22float2(feat[s2 * 64 + lane]);
        float2 v3 = __half22float2(feat[s3 * 64 + lane]);
        a0 += (v0.x + v1.x) + (v2.x + v3.x);
        a1 += (v0.y + v1.y) + (v2.y + v3.y);
    }
    for (; e < end; ++e) {
        float2 v = __half22float2(feat[csr_src[e] * 64 + lane]);
        a0 += v.x;
        a1 += v.y;
    }
    float di = deg_inv[n];
    outv[n * 64 + lane] = __float22half2_rn(make_float2(a0 * di, a1 * di));
}

__global__ __launch_bounds__(256)
void gather_mean_add_f32(const __half2* __restrict__ feat, const int* __restrict__ row_ptr,
                         const int* __restrict__ csr_src, const float* __restrict__ deg_inv,
                         float* __restrict__ out) {
    const int lane = threadIdx.x & 63;
    const int n = blockIdx.x * 4 + (threadIdx.x >> 6);
    const int beg = row_ptr[n];
    const int end = row_ptr[n + 1];
    float a0 = 0.f, a1 = 0.f;
    int e = beg;
    for (; e + 8 <= end; e += 8) {
        int s0 = csr_src[e + 0], s1 = csr_src[e + 1];
        int s2 = csr_src[e + 2], s3 = csr_src[e + 3];
        int s4 = csr_src[e + 4], s5 = csr_src[e + 5];
        int s6 = csr_src[e + 6], s7 = csr_src[e + 7];
        float2 v0 = __half22float2(feat[s0 * 64 + lane]);
        float2 v1 = __half22float2(feat[s1 * 64 + lane]);
        float2 v2 = __half22float2(feat[s2 * 64 + lane]);
        float2 v3 = __half22float2(feat[s3 * 64 + lane]);
        float2 v4 = __half22float2(feat[s4 * 64 + lane]);
        float2 v5 = __half22float2(feat[s5 * 64 + lane]);
        float2 v6 = __half22float2(feat[s6 * 64 + lane]);
        float2 v7 = __half22float2(feat[s7 * 64 + lane]);
        a0 += ((v0.x + v1.x) + (v2.x + v3.x)) + ((v4.x + v5.x) + (v6.x + v7.x));
        a1 += ((v0.y + v1.y) + (v2.y + v3.y)) + ((v4.y + v5.y) + (v6.y + v7.y));
    }
    for (; e + 4 <= end; e += 4) {
        int s0 = csr_src[e + 0], s1 = csr_src[e + 1];
        int s2 = csr_src[e + 2], s3 = csr_src[e + 3];
        float2 v0 = __half22float2(feat[s0 * 64 + lane]);
        float2 v1 = __half22float2(feat[s1 * 64 + lane]);
        float2 v2 = __half22float2(feat[s2 * 64 + lane]);
        float2 v3 = __half22float2(feat[s3 * 64 + lane]);
        a0 += (v0.x + v1.x) + (v2.x + v3.x);
        a1 += (v0.y + v1.y) + (v2.y + v3.y);
    }
    for (; e < end; ++e) {
        float2 v = __half22float2(feat[csr_src[e] * 64 + lane]);
        a0 += v.x;
        a1 += v.y;
    }
    float di = deg_inv[n];
    float2* o = (float2*)(out + (size_t)n * 128) + lane;
    float2 v = *o;
    v.x += a0 * di;
    v.y += a1 * di;
    *o = v;
}

// ---------------- MFMA fp16 GEMMs: B hoisted to registers, row-tile loop ------
// mfma_f32_16x16x32_f16 layouts (verified R4/R5):
//   A frag: lane holds A[m = lane&15][k = kc + (lane>>4)*8 + j]
//   B frag: lane holds W[n = lane&15][k = kc + (lane>>4)*8 + j]  (W row-major [J,K])
//   C/D:    col = lane&15 (n), row = (lane>>4)*4 + reg

__global__ __launch_bounds__(256, 2)
void gemm_l1(const __half* __restrict__ Aa, const __half* __restrict__ Ba,
             const __half* __restrict__ Ab, const __half* __restrict__ Bb,
             const float* __restrict__ bias, __half* __restrict__ H) {
    const int lane = threadIdx.x & 63;
    const int wave = threadIdx.x >> 6;      // owns cols [wave*64, wave*64+64)
    const int quad = lane >> 4;
    const int l16 = lane & 15;
    const int koff = quad * 8;

    f16x8 bf[2][4][4];                       // 128 VGPRs of B fragments
    #pragma unroll
    for (int p = 0; p < 2; ++p) {
        const __half* __restrict__ B = p ? Bb : Ba;
        #pragma unroll
        for (int kc = 0; kc < 4; ++kc)
            #pragma unroll
            for (int nt = 0; nt < 4; ++nt)
                bf[p][kc][nt] = *(const f16x8*)(
                    B + (size_t)(wave * 64 + nt * 16 + l16) * D_IN + kc * 32 + koff);
    }
    float bv[4];
    #pragma unroll
    for (int nt = 0; nt < 4; ++nt) bv[nt] = bias[wave * 64 + nt * 16 + l16];

    const int NT = N_NODES / 16;            // 3125 exact
    const int g = gridDim.x;

    auto loadA = [&](int t, f16x8 (&a)[2][4]) {
        const size_t arow = (size_t)(t * 16 + l16) * D_IN + koff;
        #pragma unroll
        for (int kc = 0; kc < 4; ++kc) {
            a[0][kc] = *(const f16x8*)(Aa + arow + kc * 32);
            a[1][kc] = *(const f16x8*)(Ab + arow + kc * 32);
        }
    };
    auto step = [&](int tile, const f16x8 (&a)[2][4]) {
        f32x4 acc[4] = {};
        #pragma unroll
        for (int p = 0; p < 2; ++p)
            #pragma unroll
            for (int kc = 0; kc < 4; ++kc)
                #pragma unroll
                for (int nt = 0; nt < 4; ++nt)
                    acc[nt] = __builtin_amdgcn_mfma_f32_16x16x32_f16(
                        a[p][kc], bf[p][kc][nt], acc[nt], 0, 0, 0);
        #pragma unroll
        for (int nt = 0; nt < 4; ++nt) {
            int col = wave * 64 + nt * 16 + l16;
            #pragma unroll
            for (int r = 0; r < 4; ++r) {
                int row = tile * 16 + quad * 4 + r;
                H[(size_t)row * D_HID + col] =
                    __float2half(fmaxf(acc[nt][r] + bv[nt], 0.f));
            }
        }
    };

    f16x8 A0[2][4], A1[2][4];
    int tile = blockIdx.x;
    loadA(tile, A0);
    while (true) {
        if (tile + g < NT) loadA(tile + g, A1);
        step(tile, A0);
        tile += g;
        if (tile >= NT) break;
        if (tile + g < NT) loadA(tile + g, A0);
        step(tile, A1);
        tile += g;
        if (tile >= NT) break;
    }
}

__global__ __launch_bounds__(256, 2)
void gemm_l2(const __half* __restrict__ Hh, const __half* __restrict__ B0,
             const __half* __restrict__ B1, const float* __restrict__ bias,
             __half* __restrict__ P, float* __restrict__ out) {
    const int lane = threadIdx.x & 63;
    const int wave = threadIdx.x >> 6;      // owns cols [wave*32, wave*32+32)
    const int quad = lane >> 4;
    const int l16 = lane & 15;
    const int koff = quad * 8;

    f16x8 bf0[8][2], bf1[8][2];             // 128 VGPRs of B fragments
    #pragma unroll
    for (int kc = 0; kc < 8; ++kc)
        #pragma unroll
        for (int nt = 0; nt < 2; ++nt) {
            size_t brow = (size_t)(wave * 32 + nt * 16 + l16) * D_HID + kc * 32 + koff;
            bf0[kc][nt] = *(const f16x8*)(B0 + brow);
            bf1[kc][nt] = *(const f16x8*)(B1 + brow);
        }
    float bv[2];
    #pragma unroll
    for (int nt = 0; nt < 2; ++nt) bv[nt] = bias[wave * 32 + nt * 16 + l16];

    const int NT = N_NODES / 16;
    const int g = gridDim.x;

    auto loadA = [&](int t, f16x8 (&a)[8]) {
        const size_t arow = (size_t)(t * 16 + l16) * D_HID + koff;
        #pragma unroll
        for (int kc = 0; kc < 8; ++kc)
            a[kc] = *(const f16x8*)(Hh + arow + kc * 32);
    };
    auto step = [&](int tile, const f16x8 (&a)[8]) {
        f32x4 acc0[2] = {};
        f32x4 acc1[2] = {};
        #pragma unroll
        for (int kc = 0; kc < 8; ++kc)
            #pragma unroll
            for (int nt = 0; nt < 2; ++nt) {
                acc0[nt] = __builtin_amdgcn_mfma_f32_16x16x32_f16(
                    a[kc], bf0[kc][nt], acc0[nt], 0, 0, 0);
                acc1[nt] = __builtin_amdgcn_mfma_f32_16x16x32_f16(
                    a[kc], bf1[kc][nt], acc1[nt], 0, 0, 0);
            }
        #pragma unroll
        for (int nt = 0; nt < 2; ++nt) {
            int col = wave * 32 + nt * 16 + l16;
            #pragma unroll
            for (int r = 0; r < 4; ++r) {
                int row = tile * 16 + quad * 4 + r;
                P[(size_t)row * D_OUT + col] = __float2half(acc0[nt][r]);
                out[(size_t)row * D_OUT + col] = acc1[nt][r] + bv[nt];
            }
        }
    };

    f16x8 A0[8], A1[8];
    int tile = blockIdx.x;
    loadA(tile, A0);
    while (true) {
        if (tile + g < NT) loadA(tile + g, A1);
        step(tile, A0);
        tile += g;
        if (tile >= NT) break;
        if (tile + g < NT) loadA(tile + g, A0);
        step(tile, A1);
        tile += g;
        if (tile >= NT) break;
    }
}

extern "C" void kernel_launch(void* const* d_in, const int* in_sizes, int n_in,
                              void* d_out, int out_size, void* d_ws, size_t ws_size,
                              hipStream_t stream) {
    const float* x   = (const float*)d_in[0];
    const float* Wl1 = (const float*)d_in[1];
    const float* bl1 = (const float*)d_in[2];
    const float* Wr1 = (const float*)d_in[3];
    const float* Wl2 = (const float*)d_in[4];
    const float* bl2 = (const float*)d_in[5];
    const float* Wr2 = (const float*)d_in[6];
    const int*   ei  = (const int*)d_in[7];
    const int* src = ei;              // edge_index[0]
    const int* dst = ei + N_EDGES;    // edge_index[1]
    float* out = (float*)d_out;

    // Workspace layout, 256B-aligned slabs (~68 MB)
    char* w = (char*)d_ws;
    auto alloc = [&](size_t bytes) {
        char* r = w;
        w += (bytes + 255) & ~(size_t)255;
        return r;
    };
    int*     deg       = (int*)alloc((size_t)N_NODES * 4);
    int*     row_ptr   = (int*)alloc((size_t)(N_NODES + 1) * 4);
    int*     cursor    = (int*)alloc((size_t)N_NODES * 4);
    int*     partial   = (int*)alloc(NCHUNK * 4);
    int*     chunkOff  = (int*)alloc(NCHUNK * 4);
    int*     csr_src   = (int*)alloc((size_t)N_EDGES * 4);
    float*   deg_inv   = (float*)alloc((size_t)N_NODES * 4);
    __half2* xb        = (__half2*)alloc((size_t)N_NODES * 64 * 4);   // x fp16
    __half2* mean1     = (__half2*)alloc((size_t)N_NODES * 64 * 4);   // mean(x) fp16
    __half*  h         = (__half*)alloc((size_t)N_NODES * 256 * 2);   // layer-1 out
    __half2* pb        = (__half2*)alloc((size_t)N_NODES * 64 * 4);   // h@Wl2^T fp16
    __half*  wl1h      = (__half*)alloc(4 * 32768 * 2);
    __half*  wr1h = wl1h + 32768;
    __half*  wl2h = wr1h + 32768;
    __half*  wr2h = wl2h + 32768;

    // CSR build (R5-proven)
    zero_deg<<<(N_NODES + 255) / 256, 256, 0, stream>>>(deg);
    deg_kernel<<<(N_EDGES + 255) / 256, 256, 0, stream>>>(dst, deg);
    chunk_sum<<<NCHUNK, 256, 0, stream>>>(deg, partial);
    chunk_scan<<<1, 256, 0, stream>>>(partial, chunkOff);
    scatter_scan<<<NCHUNK, 256, 0, stream>>>(deg, chunkOff, row_ptr, cursor, deg_inv);
    fill_csr<<<(N_EDGES + 255) / 256, 256, 0, stream>>>(src, dst, cursor, csr_src);

    // fp16 conversions
    cvt_half<<<12500, 256, 0, stream>>>(x, xb, N_NODES * 64);
    cvt_weights<<<64, 256, 0, stream>>>(Wl1, Wr1, Wl2, Wr2,
        (__half2*)wl1h, (__half2*)wr1h, (__half2*)wl2h, (__half2*)wr2h);

    // Layer 1: h = relu(mean(x) @ Wl1^T + x @ Wr1^T + bl1)
    gather_mean_h<<<12500, 256, 0, stream>>>(xb, row_ptr, csr_src, deg_inv, mean1);
    gemm_l1<<<GEMM_GRID, 256, 0, stream>>>(
        (const __half*)mean1, wl1h, (const __half*)xb, wr1h, bl1, h);

    // Layer 2 (reordered): p = h @ Wl2^T; out = h @ Wr2^T + bl2; out += mean(p)
    gemm_l2<<<GEMM_GRID, 256, 0, stream>>>(
        h, wl2h, wr2h, bl2, (__half*)pb, out);
    gather_mean_add_f32<<<12500, 256, 0, stream>>>(pb, row_ptr, csr_src, deg_inv, out);
}

// Round 9
// 266.753 us; speedup vs baseline: 6.5287x; 1.1076x over previous
//
#include <hip/hip_runtime.h>
#include <hip/hip_fp16.h>

#define N_NODES 50000
#define N_EDGES 800000
#define D_IN 128
#define D_HID 256
#define D_OUT 128
#define NCHUNK 196   // ceil(N_NODES / 256)
#define GEMM_GRID 512

typedef _Float16 f16x8 __attribute__((ext_vector_type(8)));
typedef float f32x4 __attribute__((ext_vector_type(4)));

// ---------------- CSR build: rank-split (atomic pass separated from scatter) --

__global__ void zero_deg(int* __restrict__ deg) {
    int i = blockIdx.x * blockDim.x + threadIdx.x;
    if (i < N_NODES) deg[i] = 0;
}

// Counts degree AND records each edge's within-node rank (atomic return value).
__global__ void deg_rank_kernel(const int* __restrict__ dst, int* __restrict__ deg,
                                int* __restrict__ rank) {
    int i = blockIdx.x * blockDim.x + threadIdx.x;
    if (i < N_EDGES) rank[i] = atomicAdd(&deg[dst[i]], 1);
}

__global__ void chunk_sum(const int* __restrict__ deg, int* __restrict__ partial) {
    __shared__ int s[256];
    int i = blockIdx.x * 256 + threadIdx.x;
    s[threadIdx.x] = (i < N_NODES) ? deg[i] : 0;
    __syncthreads();
    for (int off = 128; off > 0; off >>= 1) {
        if (threadIdx.x < off) s[threadIdx.x] += s[threadIdx.x + off];
        __syncthreads();
    }
    if (threadIdx.x == 0) partial[blockIdx.x] = s[0];
}

__global__ void chunk_scan(const int* __restrict__ partial, int* __restrict__ chunkOff) {
    __shared__ int s[256];
    int tid = threadIdx.x;
    int v = (tid < NCHUNK) ? partial[tid] : 0;
    s[tid] = v;
    __syncthreads();
    for (int off = 1; off < 256; off <<= 1) {
        int t = (tid >= off) ? s[tid - off] : 0;
        __syncthreads();
        s[tid] += t;
        __syncthreads();
    }
    if (tid < NCHUNK) chunkOff[tid] = s[tid] - v;   // exclusive
}

__global__ void scatter_scan(const int* __restrict__ deg, const int* __restrict__ chunkOff,
                             int* __restrict__ row_ptr, float* __restrict__ deg_inv) {
    __shared__ int s[256];
    int tid = threadIdx.x;
    int i = blockIdx.x * 256 + tid;
    int v = (i < N_NODES) ? deg[i] : 0;
    s[tid] = v;
    __syncthreads();
    for (int off = 1; off < 256; off <<= 1) {
        int t = (tid >= off) ? s[tid - off] : 0;
        __syncthreads();
        s[tid] += t;
        __syncthreads();
    }
    if (i < N_NODES) {
        int rp = chunkOff[blockIdx.x] + s[tid] - v;   // exclusive scan value
        row_ptr[i] = rp;
        deg_inv[i] = 1.0f / fmaxf((float)v, 1.0f);
        if (i == N_NODES - 1) row_ptr[N_NODES] = N_EDGES;
    }
}

// Atomic-free scatter: position = row_ptr[dst] + rank. Fire-and-forget stores.
__global__ void fill_csr(const int* __restrict__ src, const int* __restrict__ dst,
                         const int* __restrict__ rank, const int* __restrict__ row_ptr,
                         int* __restrict__ csr_src) {
    int e = blockIdx.x * blockDim.x + threadIdx.x;
    if (e < N_EDGES) {
        csr_src[row_ptr[dst[e]] + rank[e]] = src[e];
    }
}

// ---------------- fp32 -> fp16 conversion ----------------

__global__ void cvt_half(const float* __restrict__ in, __half2* __restrict__ out, int n2) {
    int i = blockIdx.x * blockDim.x + threadIdx.x;
    if (i < n2) {
        float2 v = ((const float2*)in)[i];
        out[i] = __float22half2_rn(v);
    }
}

__global__ void cvt_weights(const float* __restrict__ a, const float* __restrict__ b,
                            const float* __restrict__ c, const float* __restrict__ d,
                            __half2* __restrict__ oa, __half2* __restrict__ ob,
                            __half2* __restrict__ oc, __half2* __restrict__ od) {
    int i = blockIdx.x * 256 + threadIdx.x;   // 16384 half2 per matrix
    if (i < 16384) {
        oa[i] = __float22half2_rn(((const float2*)a)[i]);
        ob[i] = __float22half2_rn(((const float2*)b)[i]);
        oc[i] = __float22half2_rn(((const float2*)c)[i]);
        od[i] = __float22half2_rn(((const float2*)d)[i]);
    }
}

// ---------------- mean aggregation (CSR gather, wave-per-node, ILP-8) ---------

__global__ __launch_bounds__(256)
void gather_mean_h(const __half2* __restrict__ feat, const int* __restrict__ row_ptr,
                   const int* __restrict__ csr_src, const float* __restrict__ deg_inv,
                   __half2* __restrict__ outv) {
    const int lane = threadIdx.x & 63;
    const int n = blockIdx.x * 4 + (threadIdx.x >> 6);   // grid exactly covers N_NODES
    const int beg = row_ptr[n];
    const int end = row_ptr[n + 1];
    float a0 = 0.f, a1 = 0.f;
    int e = beg;
    for (; e + 8 <= end; e += 8) {          // 8 independent row loads in flight
        int s0 = csr_src[e + 0], s1 = csr_src[e + 1];
        int s2 = csr_src[e + 2], s3 = csr_src[e + 3];
        int s4 = csr_src[e + 4], s5 = csr_src[e + 5];
        int s6 = csr_src[e + 6], s7 = csr_src[e + 7];
        float2 v0 = __half22float2(feat[s0 * 64 + lane]);
        float2 v1 = __half22float2(feat[s1 * 64 + lane]);
        float2 v2 = __half22float2(feat[s2 * 64 + lane]);
        float2 v3 = __half22float2(feat[s3 * 64 + lane]);
        float2 v4 = __half22float2(feat[s4 * 64 + lane]);
        float2 v5 = __half22float2(feat[s5 * 64 + lane]);
        float2 v6 = __half22float2(feat[s6 * 64 + lane]);
        float2 v7 = __half22float2(feat[s7 * 64 + lane]);
        a0 += ((v0.x + v1.x) + (v2.x + v3.x)) + ((v4.x + v5.x) + (v6.x + v7.x));
        a1 += ((v0.y + v1.y) + (v2.y + v3.y)) + ((v4.y + v5.y) + (v6.y + v7.y));
    }
    for (; e + 4 <= end; e += 4) {
        int s0 = csr_src[e + 0], s1 = csr_src[e + 1];
        int s2 = csr_src[e + 2], s3 = csr_src[e + 3];
        float2 v0 = __half22float2(feat[s0 * 64 + lane]);
        float2 v1 = __half22float2(feat[s1 * 64 + lane]);
        float2 v2 = __half22float2(feat[s2 * 64 + lane]);
        float2 v3 = __half22float2(feat[s3 * 64 + lane]);
        a0 += (v0.x + v1.x) + (v2.x + v3.x);
        a1 += (v0.y + v1.y) + (v2.y + v3.y);
    }
    for (; e < end; ++e) {
        float2 v = __half22float2(feat[csr_src[e] * 64 + lane]);
        a0 += v.x;
        a1 += v.y;
    }
    float di = deg_inv[n];
    outv[n * 64 + lane] = __float22half2_rn(make_float2(a0 * di, a1 * di));
}

__global__ __launch_bounds__(256)
void gather_mean_add_f32(const __half2* __restrict__ feat, const int* __restrict__ row_ptr,
                         const int* __restrict__ csr_src, const float* __restrict__ deg_inv,
                         float* __restrict__ out) {
    const int lane = threadIdx.x & 63;
    const int n = blockIdx.x * 4 + (threadIdx.x >> 6);
    const int beg = row_ptr[n];
    const int end = row_ptr[n + 1];
    float a0 = 0.f, a1 = 0.f;
    int e = beg;
    for (; e + 8 <= end; e += 8) {
        int s0 = csr_src[e + 0], s1 = csr_src[e + 1];
        int s2 = csr_src[e + 2], s3 = csr_src[e + 3];
        int s4 = csr_src[e + 4], s5 = csr_src[e + 5];
        int s6 = csr_src[e + 6], s7 = csr_src[e + 7];
        float2 v0 = __half22float2(feat[s0 * 64 + lane]);
        float2 v1 = __half22float2(feat[s1 * 64 + lane]);
        float2 v2 = __half22float2(feat[s2 * 64 + lane]);
        float2 v3 = __half22float2(feat[s3 * 64 + lane]);
        float2 v4 = __half22float2(feat[s4 * 64 + lane]);
        float2 v5 = __half22float2(feat[s5 * 64 + lane]);
        float2 v6 = __half22float2(feat[s6 * 64 + lane]);
        float2 v7 = __half22float2(feat[s7 * 64 + lane]);
        a0 += ((v0.x + v1.x) + (v2.x + v3.x)) + ((v4.x + v5.x) + (v6.x + v7.x));
        a1 += ((v0.y + v1.y) + (v2.y + v3.y)) + ((v4.y + v5.y) + (v6.y + v7.y));
    }
    for (; e + 4 <= end; e += 4) {
        int s0 = csr_src[e + 0], s1 = csr_src[e + 1];
        int s2 = csr_src[e + 2], s3 = csr_src[e + 3];
        float2 v0 = __half22float2(feat[s0 * 64 + lane]);
        float2 v1 = __half22float2(feat[s1 * 64 + lane]);
        float2 v2 = __half22float2(feat[s2 * 64 + lane]);
        float2 v3 = __half22float2(feat[s3 * 64 + lane]);
        a0 += (v0.x + v1.x) + (v2.x + v3.x);
        a1 += (v0.y + v1.y) + (v2.y + v3.y);
    }
    for (; e < end; ++e) {
        float2 v = __half22float2(feat[csr_src[e] * 64 + lane]);
        a0 += v.x;
        a1 += v.y;
    }
    float di = deg_inv[n];
    float2* o = (float2*)(out + (size_t)n * 128) + lane;
    float2 v = *o;
    v.x += a0 * di;
    v.y += a1 * di;
    *o = v;
}

// ---------------- MFMA fp16 GEMMs: B hoisted to registers, row-tile loop ------
// mfma_f32_16x16x32_f16 layouts (verified R4/R5):
//   A frag: lane holds A[m = lane&15][k = kc + (lane>>4)*8 + j]
//   B frag: lane holds W[n = lane&15][k = kc + (lane>>4)*8 + j]  (W row-major [J,K])
//   C/D:    col = lane&15 (n), row = (lane>>4)*4 + reg

__global__ __launch_bounds__(256, 2)
void gemm_l1(const __half* __restrict__ Aa, const __half* __restrict__ Ba,
             const __half* __restrict__ Ab, const __half* __restrict__ Bb,
             const float* __restrict__ bias, __half* __restrict__ H) {
    const int lane = threadIdx.x & 63;
    const int wave = threadIdx.x >> 6;      // owns cols [wave*64, wave*64+64)
    const int quad = lane >> 4;
    const int l16 = lane & 15;
    const int koff = quad * 8;

    f16x8 bf[2][4][4];                       // 128 VGPRs of B fragments
    #pragma unroll
    for (int p = 0; p < 2; ++p) {
        const __half* __restrict__ B = p ? Bb : Ba;
        #pragma unroll
        for (int kc = 0; kc < 4; ++kc)
            #pragma unroll
            for (int nt = 0; nt < 4; ++nt)
                bf[p][kc][nt] = *(const f16x8*)(
                    B + (size_t)(wave * 64 + nt * 16 + l16) * D_IN + kc * 32 + koff);
    }
    float bv[4];
    #pragma unroll
    for (int nt = 0; nt < 4; ++nt) bv[nt] = bias[wave * 64 + nt * 16 + l16];

    const int NT = N_NODES / 16;            // 3125 exact
    const int g = gridDim.x;

    auto loadA = [&](int t, f16x8 (&a)[2][4]) {
        const size_t arow = (size_t)(t * 16 + l16) * D_IN + koff;
        #pragma unroll
        for (int kc = 0; kc < 4; ++kc) {
            a[0][kc] = *(const f16x8*)(Aa + arow + kc * 32);
            a[1][kc] = *(const f16x8*)(Ab + arow + kc * 32);
        }
    };
    auto step = [&](int tile, const f16x8 (&a)[2][4]) {
        f32x4 acc[4] = {};
        #pragma unroll
        for (int p = 0; p < 2; ++p)
            #pragma unroll
            for (int kc = 0; kc < 4; ++kc)
                #pragma unroll
                for (int nt = 0; nt < 4; ++nt)
                    acc[nt] = __builtin_amdgcn_mfma_f32_16x16x32_f16(
                        a[p][kc], bf[p][kc][nt], acc[nt], 0, 0, 0);
        #pragma unroll
        for (int nt = 0; nt < 4; ++nt) {
            int col = wave * 64 + nt * 16 + l16;
            #pragma unroll
            for (int r = 0; r < 4; ++r) {
                int row = tile * 16 + quad * 4 + r;
                H[(size_t)row * D_HID + col] =
                    __float2half(fmaxf(acc[nt][r] + bv[nt], 0.f));
            }
        }
    };

    f16x8 A0[2][4], A1[2][4];
    int tile = blockIdx.x;
    loadA(tile, A0);
    while (true) {
        if (tile + g < NT) loadA(tile + g, A1);
        step(tile, A0);
        tile += g;
        if (tile >= NT) break;
        if (tile + g < NT) loadA(tile + g, A0);
        step(tile, A1);
        tile += g;
        if (tile >= NT) break;
    }
}

__global__ __launch_bounds__(256, 2)
void gemm_l2(const __half* __restrict__ Hh, const __half* __restrict__ B0,
             const __half* __restrict__ B1, const float* __restrict__ bias,
             __half* __restrict__ P, float* __restrict__ out) {
    const int lane = threadIdx.x & 63;
    const int wave = threadIdx.x >> 6;      // owns cols [wave*32, wave*32+32)
    const int quad = lane >> 4;
    const int l16 = lane & 15;
    const int koff = quad * 8;

    f16x8 bf0[8][2], bf1[8][2];             // 128 VGPRs of B fragments
    #pragma unroll
    for (int kc = 0; kc < 8; ++kc)
        #pragma unroll
        for (int nt = 0; nt < 2; ++nt) {
            size_t brow = (size_t)(wave * 32 + nt * 16 + l16) * D_HID + kc * 32 + koff;
            bf0[kc][nt] = *(const f16x8*)(B0 + brow);
            bf1[kc][nt] = *(const f16x8*)(B1 + brow);
        }
    float bv[2];
    #pragma unroll
    for (int nt = 0; nt < 2; ++nt) bv[nt] = bias[wave * 32 + nt * 16 + l16];

    const int NT = N_NODES / 16;
    const int g = gridDim.x;

    auto loadA = [&](int t, f16x8 (&a)[8]) {
        const size_t arow = (size_t)(t * 16 + l16) * D_HID + koff;
        #pragma unroll
        for (int kc = 0; kc < 8; ++kc)
            a[kc] = *(const f16x8*)(Hh + arow + kc * 32);
    };
    auto step = [&](int tile, const f16x8 (&a)[8]) {
        f32x4 acc0[2] = {};
        f32x4 acc1[2] = {};
        #pragma unroll
        for (int kc = 0; kc < 8; ++kc)
            #pragma unroll
            for (int nt = 0; nt < 2; ++nt) {
                acc0[nt] = __builtin_amdgcn_mfma_f32_16x16x32_f16(
                    a[kc], bf0[kc][nt], acc0[nt], 0, 0, 0);
                acc1[nt] = __builtin_amdgcn_mfma_f32_16x16x32_f16(
                    a[kc], bf1[kc][nt], acc1[nt], 0, 0, 0);
            }
        #pragma unroll
        for (int nt = 0; nt < 2; ++nt) {
            int col = wave * 32 + nt * 16 + l16;
            #pragma unroll
            for (int r = 0; r < 4; ++r) {
                int row = tile * 16 + quad * 4 + r;
                P[(size_t)row * D_OUT + col] = __float2half(acc0[nt][r]);
                out[(size_t)row * D_OUT + col] = acc1[nt][r] + bv[nt];
            }
        }
    };

    f16x8 A0[8], A1[8];
    int tile = blockIdx.x;
    loadA(tile, A0);
    while (true) {
        if (tile + g < NT) loadA(tile + g, A1);
        step(tile, A0);
        tile += g;
        if (tile >= NT) break;
        if (tile + g < NT) loadA(tile + g, A0);
        step(tile, A1);
        tile += g;
        if (tile >= NT) break;
    }
}

extern "C" void kernel_launch(void* const* d_in, const int* in_sizes, int n_in,
                              void* d_out, int out_size, void* d_ws, size_t ws_size,
                              hipStream_t stream) {
    const float* x   = (const float*)d_in[0];
    const float* Wl1 = (const float*)d_in[1];
    const float* bl1 = (const float*)d_in[2];
    const float* Wr1 = (const float*)d_in[3];
    const float* Wl2 = (const float*)d_in[4];
    const float* bl2 = (const float*)d_in[5];
    const float* Wr2 = (const float*)d_in[6];
    const int*   ei  = (const int*)d_in[7];
    const int* src = ei;              // edge_index[0]
    const int* dst = ei + N_EDGES;    // edge_index[1]
    float* out = (float*)d_out;

    // Workspace layout, 256B-aligned slabs (~71 MB)
    char* w = (char*)d_ws;
    auto alloc = [&](size_t bytes) {
        char* r = w;
        w += (bytes + 255) & ~(size_t)255;
        return r;
    };
    int*     deg       = (int*)alloc((size_t)N_NODES * 4);
    int*     row_ptr   = (int*)alloc((size_t)(N_NODES + 1) * 4);
    int*     rank      = (int*)alloc((size_t)N_EDGES * 4);
    int*     partial   = (int*)alloc(NCHUNK * 4);
    int*     chunkOff  = (int*)alloc(NCHUNK * 4);
    int*     csr_src   = (int*)alloc((size_t)N_EDGES * 4);
    float*   deg_inv   = (float*)alloc((size_t)N_NODES * 4);
    __half2* xb        = (__half2*)alloc((size_t)N_NODES * 64 * 4);   // x fp16
    __half2* mean1     = (__half2*)alloc((size_t)N_NODES * 64 * 4);   // mean(x) fp16
    __half*  h         = (__half*)alloc((size_t)N_NODES * 256 * 2);   // layer-1 out
    __half2* pb        = (__half2*)alloc((size_t)N_NODES * 64 * 4);   // h@Wl2^T fp16
    __half*  wl1h      = (__half*)alloc(4 * 32768 * 2);
    __half*  wr1h = wl1h + 32768;
    __half*  wl2h = wr1h + 32768;
    __half*  wr2h = wl2h + 32768;

    // CSR build: rank-split (atomics decoupled from scatter stores)
    zero_deg<<<(N_NODES + 255) / 256, 256, 0, stream>>>(deg);
    deg_rank_kernel<<<(N_EDGES + 255) / 256, 256, 0, stream>>>(dst, deg, rank);
    chunk_sum<<<NCHUNK, 256, 0, stream>>>(deg, partial);
    chunk_scan<<<1, 256, 0, stream>>>(partial, chunkOff);
    scatter_scan<<<NCHUNK, 256, 0, stream>>>(deg, chunkOff, row_ptr, deg_inv);
    fill_csr<<<(N_EDGES + 255) / 256, 256, 0, stream>>>(src, dst, rank, row_ptr, csr_src);

    // fp16 conversions
    cvt_half<<<12500, 256, 0, stream>>>(x, xb, N_NODES * 64);
    cvt_weights<<<64, 256, 0, stream>>>(Wl1, Wr1, Wl2, Wr2,
        (__half2*)wl1h, (__half2*)wr1h, (__half2*)wl2h, (__half2*)wr2h);

    // Layer 1: h = relu(mean(x) @ Wl1^T + x @ Wr1^T + bl1)
    gather_mean_h<<<12500, 256, 0, stream>>>(xb, row_ptr, csr_src, deg_inv, mean1);
    gemm_l1<<<GEMM_GRID, 256, 0, stream>>>(
        (const __half*)mean1, wl1h, (const __half*)xb, wr1h, bl1, h);

    // Layer 2 (reordered): p = h @ Wl2^T; out = h @ Wr2^T + bl2; out += mean(p)
    gemm_l2<<<GEMM_GRID, 256, 0, stream>>>(
        h, wl2h, wr2h, bl2, (__half*)pb, out);
    gather_mean_add_f32<<<12500, 256, 0, stream>>>(pb, row_ptr, csr_src, deg_inv, out);
}

// Round 10
// 263.493 us; speedup vs baseline: 6.6094x; 1.0124x over previous
//
#include <hip/hip_runtime.h>
#include <hip/hip_fp16.h>

#define N_NODES 50000
#define N_EDGES 800000
#define D_IN 128
#define D_HID 256
#define D_OUT 128
#define NCHUNK 196   // ceil(N_NODES / 256)
#define GEMM_GRID 512

typedef _Float16 f16x8 __attribute__((ext_vector_type(8)));
typedef float f32x4 __attribute__((ext_vector_type(4)));

// ---------------- CSR build: rank-split (atomic pass separated from scatter) --

__global__ void zero_deg(int* __restrict__ deg) {
    int i = blockIdx.x * blockDim.x + threadIdx.x;
    if (i < N_NODES) deg[i] = 0;
}

// Counts degree AND records each edge's within-node rank (atomic return value).
__global__ void deg_rank_kernel(const int* __restrict__ dst, int* __restrict__ deg,
                                int* __restrict__ rank) {
    int i = blockIdx.x * blockDim.x + threadIdx.x;
    if (i < N_EDGES) rank[i] = atomicAdd(&deg[dst[i]], 1);
}

__global__ void chunk_sum(const int* __restrict__ deg, int* __restrict__ partial) {
    __shared__ int s[256];
    int i = blockIdx.x * 256 + threadIdx.x;
    s[threadIdx.x] = (i < N_NODES) ? deg[i] : 0;
    __syncthreads();
    for (int off = 128; off > 0; off >>= 1) {
        if (threadIdx.x < off) s[threadIdx.x] += s[threadIdx.x + off];
        __syncthreads();
    }
    if (threadIdx.x == 0) partial[blockIdx.x] = s[0];
}

__global__ void chunk_scan(const int* __restrict__ partial, int* __restrict__ chunkOff) {
    __shared__ int s[256];
    int tid = threadIdx.x;
    int v = (tid < NCHUNK) ? partial[tid] : 0;
    s[tid] = v;
    __syncthreads();
    for (int off = 1; off < 256; off <<= 1) {
        int t = (tid >= off) ? s[tid - off] : 0;
        __syncthreads();
        s[tid] += t;
        __syncthreads();
    }
    if (tid < NCHUNK) chunkOff[tid] = s[tid] - v;   // exclusive
}

__global__ void scatter_scan(const int* __restrict__ deg, const int* __restrict__ chunkOff,
                             int* __restrict__ row_ptr, float* __restrict__ deg_inv) {
    __shared__ int s[256];
    int tid = threadIdx.x;
    int i = blockIdx.x * 256 + tid;
    int v = (i < N_NODES) ? deg[i] : 0;
    s[tid] = v;
    __syncthreads();
    for (int off = 1; off < 256; off <<= 1) {
        int t = (tid >= off) ? s[tid - off] : 0;
        __syncthreads();
        s[tid] += t;
        __syncthreads();
    }
    if (i < N_NODES) {
        int rp = chunkOff[blockIdx.x] + s[tid] - v;   // exclusive scan value
        row_ptr[i] = rp;
        deg_inv[i] = 1.0f / fmaxf((float)v, 1.0f);
        if (i == N_NODES - 1) row_ptr[N_NODES] = N_EDGES;
    }
}

// Atomic-free scatter: position = row_ptr[dst] + rank. Fire-and-forget stores.
__global__ void fill_csr(const int* __restrict__ src, const int* __restrict__ dst,
                         const int* __restrict__ rank, const int* __restrict__ row_ptr,
                         int* __restrict__ csr_src) {
    int e = blockIdx.x * blockDim.x + threadIdx.x;
    if (e < N_EDGES) {
        csr_src[row_ptr[dst[e]] + rank[e]] = src[e];
    }
}

// ---------------- fp32 -> fp16 conversion ----------------

__global__ void cvt_half(const float* __restrict__ in, __half2* __restrict__ out, int n2) {
    int i = blockIdx.x * blockDim.x + threadIdx.x;
    if (i < n2) {
        float2 v = ((const float2*)in)[i];
        out[i] = __float22half2_rn(v);
    }
}

__global__ void cvt_weights(const float* __restrict__ a, const float* __restrict__ b,
                            const float* __restrict__ c, const float* __restrict__ d,
                            __half2* __restrict__ oa, __half2* __restrict__ ob,
                            __half2* __restrict__ oc, __half2* __restrict__ od) {
    int i = blockIdx.x * 256 + threadIdx.x;   // 16384 half2 per matrix
    if (i < 16384) {
        oa[i] = __float22half2_rn(((const float2*)a)[i]);
        ob[i] = __float22half2_rn(((const float2*)b)[i]);
        oc[i] = __float22half2_rn(((const float2*)c)[i]);
        od[i] = __float22half2_rn(((const float2*)d)[i]);
    }
}

// ---------------- mean aggregation: 4 edges/wave-instruction ------------------
// Wave per node. 4 groups of 16 lanes; group g reads edge e+g's row with
// float4 (=4 half2 = 8 feats per lane, 16 lanes = 256 B row). One instruction
// fetches 4 rows (1 KB). Cross-group reduce: shfl_xor 16/32. Group 0 writes.

__device__ __forceinline__ void accum_row4(const float4* __restrict__ feat4,
                                           int src, int s, float (&acc)[8]) {
    float4 v = feat4[(size_t)src * 16 + s];
    const __half2* hp = (const __half2*)&v;
    float2 f0 = __half22float2(hp[0]);
    float2 f1 = __half22float2(hp[1]);
    float2 f2 = __half22float2(hp[2]);
    float2 f3 = __half22float2(hp[3]);
    acc[0] += f0.x; acc[1] += f0.y;
    acc[2] += f1.x; acc[3] += f1.y;
    acc[4] += f2.x; acc[5] += f2.y;
    acc[6] += f3.x; acc[7] += f3.y;
}

__global__ __launch_bounds__(256)
void gather_mean_h(const __half2* __restrict__ feat, const int* __restrict__ row_ptr,
                   const int* __restrict__ csr_src, const float* __restrict__ deg_inv,
                   __half2* __restrict__ outv) {
    const float4* feat4 = (const float4*)feat;
    const int lane = threadIdx.x & 63;
    const int g = lane >> 4;          // edge slot 0..3
    const int s = lane & 15;          // 16B chunk within row
    const int n = blockIdx.x * 4 + (threadIdx.x >> 6);
    const int beg = row_ptr[n];
    const int end = row_ptr[n + 1];
    float acc[8] = {};
    int e = beg;
    for (; e + 8 <= end; e += 8) {    // 2 independent 4-row loads in flight
        int s0 = csr_src[e + g];
        int s1 = csr_src[e + 4 + g];
        accum_row4(feat4, s0, s, acc);
        accum_row4(feat4, s1, s, acc);
    }
    for (; e + 4 <= end; e += 4) {
        int s0 = csr_src[e + g];
        accum_row4(feat4, s0, s, acc);
    }
    if (e < end) {                    // masked tail (1..3 edges)
        int r = end - e;
        if (g < r) {
            int s0 = csr_src[e + g];
            accum_row4(feat4, s0, s, acc);
        }
    }
    #pragma unroll
    for (int j = 0; j < 8; ++j) {
        acc[j] += __shfl_xor(acc[j], 16);
        acc[j] += __shfl_xor(acc[j], 32);
    }
    if (g == 0) {
        float di = deg_inv[n];
        float4 o;
        __half2* op = (__half2*)&o;
        op[0] = __float22half2_rn(make_float2(acc[0] * di, acc[1] * di));
        op[1] = __float22half2_rn(make_float2(acc[2] * di, acc[3] * di));
        op[2] = __float22half2_rn(make_float2(acc[4] * di, acc[5] * di));
        op[3] = __float22half2_rn(make_float2(acc[6] * di, acc[7] * di));
        ((float4*)(outv + (size_t)n * 64))[s] = o;
    }
}

__global__ __launch_bounds__(256)
void gather_mean_add_f32(const __half2* __restrict__ feat, const int* __restrict__ row_ptr,
                         const int* __restrict__ csr_src, const float* __restrict__ deg_inv,
                         float* __restrict__ out) {
    const float4* feat4 = (const float4*)feat;
    const int lane = threadIdx.x & 63;
    const int g = lane >> 4;
    const int s = lane & 15;
    const int n = blockIdx.x * 4 + (threadIdx.x >> 6);
    const int beg = row_ptr[n];
    const int end = row_ptr[n + 1];
    float acc[8] = {};
    int e = beg;
    for (; e + 8 <= end; e += 8) {
        int s0 = csr_src[e + g];
        int s1 = csr_src[e + 4 + g];
        accum_row4(feat4, s0, s, acc);
        accum_row4(feat4, s1, s, acc);
    }
    for (; e + 4 <= end; e += 4) {
        int s0 = csr_src[e + g];
        accum_row4(feat4, s0, s, acc);
    }
    if (e < end) {
        int r = end - e;
        if (g < r) {
            int s0 = csr_src[e + g];
            accum_row4(feat4, s0, s, acc);
        }
    }
    #pragma unroll
    for (int j = 0; j < 8; ++j) {
        acc[j] += __shfl_xor(acc[j], 16);
        acc[j] += __shfl_xor(acc[j], 32);
    }
    if (g == 0) {
        float di = deg_inv[n];
        float4* orow = (float4*)(out + (size_t)n * 128);  // 32 float4 chunks
        float4 o0 = orow[s * 2];
        float4 o1 = orow[s * 2 + 1];
        o0.x += acc[0] * di; o0.y += acc[1] * di;
        o0.z += acc[2] * di; o0.w += acc[3] * di;
        o1.x += acc[4] * di; o1.y += acc[5] * di;
        o1.z += acc[6] * di; o1.w += acc[7] * di;
        orow[s * 2] = o0;
        orow[s * 2 + 1] = o1;
    }
}

// ---------------- MFMA fp16 GEMMs: B hoisted to registers, row-tile loop ------
// mfma_f32_16x16x32_f16 layouts (verified R4/R5):
//   A frag: lane holds A[m = lane&15][k = kc + (lane>>4)*8 + j]
//   B frag: lane holds W[n = lane&15][k = kc + (lane>>4)*8 + j]  (W row-major [J,K])
//   C/D:    col = lane&15 (n), row = (lane>>4)*4 + reg

__global__ __launch_bounds__(256, 2)
void gemm_l1(const __half* __restrict__ Aa, const __half* __restrict__ Ba,
             const __half* __restrict__ Ab, const __half* __restrict__ Bb,
             const float* __restrict__ bias, __half* __restrict__ H) {
    const int lane = threadIdx.x & 63;
    const int wave = threadIdx.x >> 6;      // owns cols [wave*64, wave*64+64)
    const int quad = lane >> 4;
    const int l16 = lane & 15;
    const int koff = quad * 8;

    f16x8 bf[2][4][4];                       // 128 VGPRs of B fragments
    #pragma unroll
    for (int p = 0; p < 2; ++p) {
        const __half* __restrict__ B = p ? Bb : Ba;
        #pragma unroll
        for (int kc = 0; kc < 4; ++kc)
            #pragma unroll
            for (int nt = 0; nt < 4; ++nt)
                bf[p][kc][nt] = *(const f16x8*)(
                    B + (size_t)(wave * 64 + nt * 16 + l16) * D_IN + kc * 32 + koff);
    }
    float bv[4];
    #pragma unroll
    for (int nt = 0; nt < 4; ++nt) bv[nt] = bias[wave * 64 + nt * 16 + l16];

    const int NT = N_NODES / 16;            // 3125 exact
    const int g = gridDim.x;

    auto loadA = [&](int t, f16x8 (&a)[2][4]) {
        const size_t arow = (size_t)(t * 16 + l16) * D_IN + koff;
        #pragma unroll
        for (int kc = 0; kc < 4; ++kc) {
            a[0][kc] = *(const f16x8*)(Aa + arow + kc * 32);
            a[1][kc] = *(const f16x8*)(Ab + arow + kc * 32);
        }
    };
    auto step = [&](int tile, const f16x8 (&a)[2][4]) {
        f32x4 acc[4] = {};
        #pragma unroll
        for (int p = 0; p < 2; ++p)
            #pragma unroll
            for (int kc = 0; kc < 4; ++kc)
                #pragma unroll
                for (int nt = 0; nt < 4; ++nt)
                    acc[nt] = __builtin_amdgcn_mfma_f32_16x16x32_f16(
                        a[p][kc], bf[p][kc][nt], acc[nt], 0, 0, 0);
        #pragma unroll
        for (int nt = 0; nt < 4; ++nt) {
            int col = wave * 64 + nt * 16 + l16;
            #pragma unroll
            for (int r = 0; r < 4; ++r) {
                int row = tile * 16 + quad * 4 + r;
                H[(size_t)row * D_HID + col] =
                    __float2half(fmaxf(acc[nt][r] + bv[nt], 0.f));
            }
        }
    };

    f16x8 A0[2][4], A1[2][4];
    int tile = blockIdx.x;
    loadA(tile, A0);
    while (true) {
        if (tile + g < NT) loadA(tile + g, A1);
        step(tile, A0);
        tile += g;
        if (tile >= NT) break;
        if (tile + g < NT) loadA(tile + g, A0);
        step(tile, A1);
        tile += g;
        if (tile >= NT) break;
    }
}

__global__ __launch_bounds__(256, 2)
void gemm_l2(const __half* __restrict__ Hh, const __half* __restrict__ B0,
             const __half* __restrict__ B1, const float* __restrict__ bias,
             __half* __restrict__ P, float* __restrict__ out) {
    const int lane = threadIdx.x & 63;
    const int wave = threadIdx.x >> 6;      // owns cols [wave*32, wave*32+32)
    const int quad = lane >> 4;
    const int l16 = lane & 15;
    const int koff = quad * 8;

    f16x8 bf0[8][2], bf1[8][2];             // 128 VGPRs of B fragments
    #pragma unroll
    for (int kc = 0; kc < 8; ++kc)
        #pragma unroll
        for (int nt = 0; nt < 2; ++nt) {
            size_t brow = (size_t)(wave * 32 + nt * 16 + l16) * D_HID + kc * 32 + koff;
            bf0[kc][nt] = *(const f16x8*)(B0 + brow);
            bf1[kc][nt] = *(const f16x8*)(B1 + brow);
        }
    float bv[2];
    #pragma unroll
    for (int nt = 0; nt < 2; ++nt) bv[nt] = bias[wave * 32 + nt * 16 + l16];

    const int NT = N_NODES / 16;
    const int g = gridDim.x;

    auto loadA = [&](int t, f16x8 (&a)[8]) {
        const size_t arow = (size_t)(t * 16 + l16) * D_HID + koff;
        #pragma unroll
        for (int kc = 0; kc < 8; ++kc)
            a[kc] = *(const f16x8*)(Hh + arow + kc * 32);
    };
    auto step = [&](int tile, const f16x8 (&a)[8]) {
        f32x4 acc0[2] = {};
        f32x4 acc1[2] = {};
        #pragma unroll
        for (int kc = 0; kc < 8; ++kc)
            #pragma unroll
            for (int nt = 0; nt < 2; ++nt) {
                acc0[nt] = __builtin_amdgcn_mfma_f32_16x16x32_f16(
                    a[kc], bf0[kc][nt], acc0[nt], 0, 0, 0);
                acc1[nt] = __builtin_amdgcn_mfma_f32_16x16x32_f16(
                    a[kc], bf1[kc][nt], acc1[nt], 0, 0, 0);
            }
        #pragma unroll
        for (int nt = 0; nt < 2; ++nt) {
            int col = wave * 32 + nt * 16 + l16;
            #pragma unroll
            for (int r = 0; r < 4; ++r) {
                int row = tile * 16 + quad * 4 + r;
                P[(size_t)row * D_OUT + col] = __float2half(acc0[nt][r]);
                out[(size_t)row * D_OUT + col] = acc1[nt][r] + bv[nt];
            }
        }
    };

    f16x8 A0[8], A1[8];
    int tile = blockIdx.x;
    loadA(tile, A0);
    while (true) {
        if (tile + g < NT) loadA(tile + g, A1);
        step(tile, A0);
        tile += g;
        if (tile >= NT) break;
        if (tile + g < NT) loadA(tile + g, A0);
        step(tile, A1);
        tile += g;
        if (tile >= NT) break;
    }
}

extern "C" void kernel_launch(void* const* d_in, const int* in_sizes, int n_in,
                              void* d_out, int out_size, void* d_ws, size_t ws_size,
                              hipStream_t stream) {
    const float* x   = (const float*)d_in[0];
    const float* Wl1 = (const float*)d_in[1];
    const float* bl1 = (const float*)d_in[2];
    const float* Wr1 = (const float*)d_in[3];
    const float* Wl2 = (const float*)d_in[4];
    const float* bl2 = (const float*)d_in[5];
    const float* Wr2 = (const float*)d_in[6];
    const int*   ei  = (const int*)d_in[7];
    const int* src = ei;              // edge_index[0]
    const int* dst = ei + N_EDGES;    // edge_index[1]
    float* out = (float*)d_out;

    // Workspace layout, 256B-aligned slabs (~71 MB)
    char* w = (char*)d_ws;
    auto alloc = [&](size_t bytes) {
        char* r = w;
        w += (bytes + 255) & ~(size_t)255;
        return r;
    };
    int*     deg       = (int*)alloc((size_t)N_NODES * 4);
    int*     row_ptr   = (int*)alloc((size_t)(N_NODES + 1) * 4);
    int*     rank      = (int*)alloc((size_t)N_EDGES * 4);
    int*     partial   = (int*)alloc(NCHUNK * 4);
    int*     chunkOff  = (int*)alloc(NCHUNK * 4);
    int*     csr_src   = (int*)alloc((size_t)N_EDGES * 4);
    float*   deg_inv   = (float*)alloc((size_t)N_NODES * 4);
    __half2* xb        = (__half2*)alloc((size_t)N_NODES * 64 * 4);   // x fp16
    __half2* mean1     = (__half2*)alloc((size_t)N_NODES * 64 * 4);   // mean(x) fp16
    __half*  h         = (__half*)alloc((size_t)N_NODES * 256 * 2);   // layer-1 out
    __half2* pb        = (__half2*)alloc((size_t)N_NODES * 64 * 4);   // h@Wl2^T fp16
    __half*  wl1h      = (__half*)alloc(4 * 32768 * 2);
    __half*  wr1h = wl1h + 32768;
    __half*  wl2h = wr1h + 32768;
    __half*  wr2h = wl2h + 32768;

    // CSR build: rank-split (atomics decoupled from scatter stores)
    zero_deg<<<(N_NODES + 255) / 256, 256, 0, stream>>>(deg);
    deg_rank_kernel<<<(N_EDGES + 255) / 256, 256, 0, stream>>>(dst, deg, rank);
    chunk_sum<<<NCHUNK, 256, 0, stream>>>(deg, partial);
    chunk_scan<<<1, 256, 0, stream>>>(partial, chunkOff);
    scatter_scan<<<NCHUNK, 256, 0, stream>>>(deg, chunkOff, row_ptr, deg_inv);
    fill_csr<<<(N_EDGES + 255) / 256, 256, 0, stream>>>(src, dst, rank, row_ptr, csr_src);

    // fp16 conversions
    cvt_half<<<12500, 256, 0, stream>>>(x, xb, N_NODES * 64);
    cvt_weights<<<64, 256, 0, stream>>>(Wl1, Wr1, Wl2, Wr2,
        (__half2*)wl1h, (__half2*)wr1h, (__half2*)wl2h, (__half2*)wr2h);

    // Layer 1: h = relu(mean(x) @ Wl1^T + x @ Wr1^T + bl1)
    gather_mean_h<<<12500, 256, 0, stream>>>(xb, row_ptr, csr_src, deg_inv, mean1);
    gemm_l1<<<GEMM_GRID, 256, 0, stream>>>(
        (const __half*)mean1, wl1h, (const __half*)xb, wr1h, bl1, h);

    // Layer 2 (reordered): p = h @ Wl2^T; out = h @ Wr2^T + bl2; out += mean(p)
    gemm_l2<<<GEMM_GRID, 256, 0, stream>>>(
        h, wl2h, wr2h, bl2, (__half*)pb, out);
    gather_mean_add_f32<<<12500, 256, 0, stream>>>(pb, row_ptr, csr_src, deg_inv, out);
}

// Round 11
// 258.627 us; speedup vs baseline: 6.7338x; 1.0188x over previous
//
#include <hip/hip_runtime.h>
#include <hip/hip_fp16.h>

#define N_NODES 50000
#define N_EDGES 800000
#define D_IN 128
#define D_HID 256
#define D_OUT 128
#define NCHUNK 196   // ceil(N_NODES / 256)
#define GEMM_GRID 512

typedef _Float16 f16x8 __attribute__((ext_vector_type(8)));
typedef float f32x4 __attribute__((ext_vector_type(4)));

// ---------------- fused prep: zero_deg + cvt x + cvt weights ------------------
// blocks [0,12500): xb; [12500,12564): 4 weight mats; [12564,12760): zero deg.

__global__ __launch_bounds__(256)
void prep_kernel(const float* __restrict__ x, __half2* __restrict__ xb,
                 const float* __restrict__ Wl1, const float* __restrict__ Wr1,
                 const float* __restrict__ Wl2, const float* __restrict__ Wr2,
                 __half2* __restrict__ wl1h, __half2* __restrict__ wr1h,
                 __half2* __restrict__ wl2h, __half2* __restrict__ wr2h,
                 int* __restrict__ deg) {
    int b = blockIdx.x;
    if (b < 12500) {
        int i = b * 256 + threadIdx.x;            // 3.2M half2
        xb[i] = __float22half2_rn(((const float2*)x)[i]);
    } else if (b < 12564) {
        int i = (b - 12500) * 256 + threadIdx.x;  // 16384 half2 per matrix
        wl1h[i] = __float22half2_rn(((const float2*)Wl1)[i]);
        wr1h[i] = __float22half2_rn(((const float2*)Wr1)[i]);
        wl2h[i] = __float22half2_rn(((const float2*)Wl2)[i]);
        wr2h[i] = __float22half2_rn(((const float2*)Wr2)[i]);
    } else {
        int i = (b - 12564) * 256 + threadIdx.x;
        if (i < N_NODES) deg[i] = 0;
    }
}

// ---------------- CSR build: rank-split (atomic pass separated from scatter) --

__global__ void deg_rank_kernel(const int* __restrict__ dst, int* __restrict__ deg,
                                int* __restrict__ rank) {
    int i = blockIdx.x * blockDim.x + threadIdx.x;
    if (i < N_EDGES) rank[i] = atomicAdd(&deg[dst[i]], 1);
}

__global__ void chunk_sum(const int* __restrict__ deg, int* __restrict__ partial) {
    __shared__ int s[256];
    int i = blockIdx.x * 256 + threadIdx.x;
    s[threadIdx.x] = (i < N_NODES) ? deg[i] : 0;
    __syncthreads();
    for (int off = 128; off > 0; off >>= 1) {
        if (threadIdx.x < off) s[threadIdx.x] += s[threadIdx.x + off];
        __syncthreads();
    }
    if (threadIdx.x == 0) partial[blockIdx.x] = s[0];
}

__global__ void chunk_scan(const int* __restrict__ partial, int* __restrict__ chunkOff) {
    __shared__ int s[256];
    int tid = threadIdx.x;
    int v = (tid < NCHUNK) ? partial[tid] : 0;
    s[tid] = v;
    __syncthreads();
    for (int off = 1; off < 256; off <<= 1) {
        int t = (tid >= off) ? s[tid - off] : 0;
        __syncthreads();
        s[tid] += t;
        __syncthreads();
    }
    if (tid < NCHUNK) chunkOff[tid] = s[tid] - v;   // exclusive
}

__global__ void scatter_scan(const int* __restrict__ deg, const int* __restrict__ chunkOff,
                             int* __restrict__ row_ptr, float* __restrict__ deg_inv) {
    __shared__ int s[256];
    int tid = threadIdx.x;
    int i = blockIdx.x * 256 + tid;
    int v = (i < N_NODES) ? deg[i] : 0;
    s[tid] = v;
    __syncthreads();
    for (int off = 1; off < 256; off <<= 1) {
        int t = (tid >= off) ? s[tid - off] : 0;
        __syncthreads();
        s[tid] += t;
        __syncthreads();
    }
    if (i < N_NODES) {
        int rp = chunkOff[blockIdx.x] + s[tid] - v;   // exclusive scan value
        row_ptr[i] = rp;
        deg_inv[i] = 1.0f / fmaxf((float)v, 1.0f);
        if (i == N_NODES - 1) row_ptr[N_NODES] = N_EDGES;
    }
}

// Atomic-free scatter: position = row_ptr[dst] + rank. Fire-and-forget stores.
__global__ void fill_csr(const int* __restrict__ src, const int* __restrict__ dst,
                         const int* __restrict__ rank, const int* __restrict__ row_ptr,
                         int* __restrict__ csr_src) {
    int e = blockIdx.x * blockDim.x + threadIdx.x;
    if (e < N_EDGES) {
        csr_src[row_ptr[dst[e]] + rank[e]] = src[e];
    }
}

// ---------------- mean aggregation: 4 edges/instruction, ILP-4 ----------------
// Wave per node. 4 groups of 16 lanes; group g reads edge e+?+g's row with
// float4 (16 lanes = 256 B row). 16 edges (4 instr) in flight per wave.
// Cross-group reduce: shfl_xor 16/32. Group 0 writes.

__device__ __forceinline__ float4 load_row4(const float4* __restrict__ feat4,
                                            int src, int s) {
    return feat4[(size_t)src * 16 + s];
}

__device__ __forceinline__ void add_row(const float4& v, float (&acc)[8]) {
    const __half2* hp = (const __half2*)&v;
    float2 f0 = __half22float2(hp[0]);
    float2 f1 = __half22float2(hp[1]);
    float2 f2 = __half22float2(hp[2]);
    float2 f3 = __half22float2(hp[3]);
    acc[0] += f0.x; acc[1] += f0.y;
    acc[2] += f1.x; acc[3] += f1.y;
    acc[4] += f2.x; acc[5] += f2.y;
    acc[6] += f3.x; acc[7] += f3.y;
}

template<bool ACCUM_F32>
__device__ __forceinline__ void gather_core(const __half2* __restrict__ feat,
                                            const int* __restrict__ row_ptr,
                                            const int* __restrict__ csr_src,
                                            const float* __restrict__ deg_inv,
                                            __half2* __restrict__ outh,
                                            float* __restrict__ outf) {
    const float4* feat4 = (const float4*)feat;
    const int lane = threadIdx.x & 63;
    const int g = lane >> 4;          // edge slot 0..3
    const int s = lane & 15;          // 16B chunk within row
    const int n = blockIdx.x * 4 + (threadIdx.x >> 6);
    const int beg = row_ptr[n];
    const int end = row_ptr[n + 1];
    float acc[8] = {};
    int e = beg;
    for (; e + 16 <= end; e += 16) {  // 4 independent 4-row loads in flight
        int s0 = csr_src[e + g];
        int s1 = csr_src[e + 4 + g];
        int s2 = csr_src[e + 8 + g];
        int s3 = csr_src[e + 12 + g];
        float4 v0 = load_row4(feat4, s0, s);
        float4 v1 = load_row4(feat4, s1, s);
        float4 v2 = load_row4(feat4, s2, s);
        float4 v3 = load_row4(feat4, s3, s);
        add_row(v0, acc);
        add_row(v1, acc);
        add_row(v2, acc);
        add_row(v3, acc);
    }
    for (; e + 4 <= end; e += 4) {
        int s0 = csr_src[e + g];
        float4 v0 = load_row4(feat4, s0, s);
        add_row(v0, acc);
    }
    if (e < end) {                    // masked tail (1..3 edges)
        if (g < end - e) {
            int s0 = csr_src[e + g];
            float4 v0 = load_row4(feat4, s0, s);
            add_row(v0, acc);
        }
    }
    #pragma unroll
    for (int j = 0; j < 8; ++j) {
        acc[j] += __shfl_xor(acc[j], 16);
        acc[j] += __shfl_xor(acc[j], 32);
    }
    if (g == 0) {
        float di = deg_inv[n];
        if (ACCUM_F32) {
            float4* orow = (float4*)(outf + (size_t)n * 128);
            float4 o0 = orow[s * 2];
            float4 o1 = orow[s * 2 + 1];
            o0.x += acc[0] * di; o0.y += acc[1] * di;
            o0.z += acc[2] * di; o0.w += acc[3] * di;
            o1.x += acc[4] * di; o1.y += acc[5] * di;
            o1.z += acc[6] * di; o1.w += acc[7] * di;
            orow[s * 2] = o0;
            orow[s * 2 + 1] = o1;
        } else {
            float4 o;
            __half2* op = (__half2*)&o;
            op[0] = __float22half2_rn(make_float2(acc[0] * di, acc[1] * di));
            op[1] = __float22half2_rn(make_float2(acc[2] * di, acc[3] * di));
            op[2] = __float22half2_rn(make_float2(acc[4] * di, acc[5] * di));
            op[3] = __float22half2_rn(make_float2(acc[6] * di, acc[7] * di));
            ((float4*)(outh + (size_t)n * 64))[s] = o;
        }
    }
}

__global__ __launch_bounds__(256)
void gather_mean_h(const __half2* __restrict__ feat, const int* __restrict__ row_ptr,
                   const int* __restrict__ csr_src, const float* __restrict__ deg_inv,
                   __half2* __restrict__ outv) {
    gather_core<false>(feat, row_ptr, csr_src, deg_inv, outv, nullptr);
}

__global__ __launch_bounds__(256)
void gather_mean_add_f32(const __half2* __restrict__ feat, const int* __restrict__ row_ptr,
                         const int* __restrict__ csr_src, const float* __restrict__ deg_inv,
                         float* __restrict__ out) {
    gather_core<true>(feat, row_ptr, csr_src, deg_inv, nullptr, out);
}

// ---------------- MFMA fp16 GEMMs: B hoisted to registers, row-tile loop ------
// mfma_f32_16x16x32_f16 layouts (verified R4/R5):
//   A frag: lane holds A[m = lane&15][k = kc + (lane>>4)*8 + j]
//   B frag: lane holds W[n = lane&15][k = kc + (lane>>4)*8 + j]  (W row-major [J,K])
//   C/D:    col = lane&15 (n), row = (lane>>4)*4 + reg

__global__ __launch_bounds__(256, 2)
void gemm_l1(const __half* __restrict__ Aa, const __half* __restrict__ Ba,
             const __half* __restrict__ Ab, const __half* __restrict__ Bb,
             const float* __restrict__ bias, __half* __restrict__ H) {
    const int lane = threadIdx.x & 63;
    const int wave = threadIdx.x >> 6;      // owns cols [wave*64, wave*64+64)
    const int quad = lane >> 4;
    const int l16 = lane & 15;
    const int koff = quad * 8;

    f16x8 bf[2][4][4];                       // 128 VGPRs of B fragments
    #pragma unroll
    for (int p = 0; p < 2; ++p) {
        const __half* __restrict__ B = p ? Bb : Ba;
        #pragma unroll
        for (int kc = 0; kc < 4; ++kc)
            #pragma unroll
            for (int nt = 0; nt < 4; ++nt)
                bf[p][kc][nt] = *(const f16x8*)(
                    B + (size_t)(wave * 64 + nt * 16 + l16) * D_IN + kc * 32 + koff);
    }
    float bv[4];
    #pragma unroll
    for (int nt = 0; nt < 4; ++nt) bv[nt] = bias[wave * 64 + nt * 16 + l16];

    const int NT = N_NODES / 16;            // 3125 exact
    const int g = gridDim.x;

    auto loadA = [&](int t, f16x8 (&a)[2][4]) {
        const size_t arow = (size_t)(t * 16 + l16) * D_IN + koff;
        #pragma unroll
        for (int kc = 0; kc < 4; ++kc) {
            a[0][kc] = *(const f16x8*)(Aa + arow + kc * 32);
            a[1][kc] = *(const f16x8*)(Ab + arow + kc * 32);
        }
    };
    auto step = [&](int tile, const f16x8 (&a)[2][4]) {
        f32x4 acc[4] = {};
        #pragma unroll
        for (int p = 0; p < 2; ++p)
            #pragma unroll
            for (int kc = 0; kc < 4; ++kc)
                #pragma unroll
                for (int nt = 0; nt < 4; ++nt)
                    acc[nt] = __builtin_amdgcn_mfma_f32_16x16x32_f16(
                        a[p][kc], bf[p][kc][nt], acc[nt], 0, 0, 0);
        #pragma unroll
        for (int nt = 0; nt < 4; ++nt) {
            int col = wave * 64 + nt * 16 + l16;
            #pragma unroll
            for (int r = 0; r < 4; ++r) {
                int row = tile * 16 + quad * 4 + r;
                H[(size_t)row * D_HID + col] =
                    __float2half(fmaxf(acc[nt][r] + bv[nt], 0.f));
            }
        }
    };

    f16x8 A0[2][4], A1[2][4];
    int tile = blockIdx.x;
    loadA(tile, A0);
    while (true) {
        if (tile + g < NT) loadA(tile + g, A1);
        step(tile, A0);
        tile += g;
        if (tile >= NT) break;
        if (tile + g < NT) loadA(tile + g, A0);
        step(tile, A1);
        tile += g;
        if (tile >= NT) break;
    }
}

__global__ __launch_bounds__(256, 2)
void gemm_l2(const __half* __restrict__ Hh, const __half* __restrict__ B0,
             const __half* __restrict__ B1, const float* __restrict__ bias,
             __half* __restrict__ P, float* __restrict__ out) {
    const int lane = threadIdx.x & 63;
    const int wave = threadIdx.x >> 6;      // owns cols [wave*32, wave*32+32)
    const int quad = lane >> 4;
    const int l16 = lane & 15;
    const int koff = quad * 8;

    f16x8 bf0[8][2], bf1[8][2];             // 128 VGPRs of B fragments
    #pragma unroll
    for (int kc = 0; kc < 8; ++kc)
        #pragma unroll
        for (int nt = 0; nt < 2; ++nt) {
            size_t brow = (size_t)(wave * 32 + nt * 16 + l16) * D_HID + kc * 32 + koff;
            bf0[kc][nt] = *(const f16x8*)(B0 + brow);
            bf1[kc][nt] = *(const f16x8*)(B1 + brow);
        }
    float bv[2];
    #pragma unroll
    for (int nt = 0; nt < 2; ++nt) bv[nt] = bias[wave * 32 + nt * 16 + l16];

    const int NT = N_NODES / 16;
    const int g = gridDim.x;

    auto loadA = [&](int t, f16x8 (&a)[8]) {
        const size_t arow = (size_t)(t * 16 + l16) * D_HID + koff;
        #pragma unroll
        for (int kc = 0; kc < 8; ++kc)
            a[kc] = *(const f16x8*)(Hh + arow + kc * 32);
    };
    auto step = [&](int tile, const f16x8 (&a)[8]) {
        f32x4 acc0[2] = {};
        f32x4 acc1[2] = {};
        #pragma unroll
        for (int kc = 0; kc < 8; ++kc)
            #pragma unroll
            for (int nt = 0; nt < 2; ++nt) {
                acc0[nt] = __builtin_amdgcn_mfma_f32_16x16x32_f16(
                    a[kc], bf0[kc][nt], acc0[nt], 0, 0, 0);
                acc1[nt] = __builtin_amdgcn_mfma_f32_16x16x32_f16(
                    a[kc], bf1[kc][nt], acc1[nt], 0, 0, 0);
            }
        #pragma unroll
        for (int nt = 0; nt < 2; ++nt) {
            int col = wave * 32 + nt * 16 + l16;
            #pragma unroll
            for (int r = 0; r < 4; ++r) {
                int row = tile * 16 + quad * 4 + r;
                P[(size_t)row * D_OUT + col] = __float2half(acc0[nt][r]);
                out[(size_t)row * D_OUT + col] = acc1[nt][r] + bv[nt];
            }
        }
    };

    f16x8 A0[8], A1[8];
    int tile = blockIdx.x;
    loadA(tile, A0);
    while (true) {
        if (tile + g < NT) loadA(tile + g, A1);
        step(tile, A0);
        tile += g;
        if (tile >= NT) break;
        if (tile + g < NT) loadA(tile + g, A0);
        step(tile, A1);
        tile += g;
        if (tile >= NT) break;
    }
}

extern "C" void kernel_launch(void* const* d_in, const int* in_sizes, int n_in,
                              void* d_out, int out_size, void* d_ws, size_t ws_size,
                              hipStream_t stream) {
    const float* x   = (const float*)d_in[0];
    const float* Wl1 = (const float*)d_in[1];
    const float* bl1 = (const float*)d_in[2];
    const float* Wr1 = (const float*)d_in[3];
    const float* Wl2 = (const float*)d_in[4];
    const float* bl2 = (const float*)d_in[5];
    const float* Wr2 = (const float*)d_in[6];
    const int*   ei  = (const int*)d_in[7];
    const int* src = ei;              // edge_index[0]
    const int* dst = ei + N_EDGES;    // edge_index[1]
    float* out = (float*)d_out;

    // Workspace layout, 256B-aligned slabs (~71 MB)
    char* w = (char*)d_ws;
    auto alloc = [&](size_t bytes) {
        char* r = w;
        w += (bytes + 255) & ~(size_t)255;
        return r;
    };
    int*     deg       = (int*)alloc((size_t)N_NODES * 4);
    int*     row_ptr   = (int*)alloc((size_t)(N_NODES + 1) * 4);
    int*     rank      = (int*)alloc((size_t)N_EDGES * 4);
    int*     partial   = (int*)alloc(NCHUNK * 4);
    int*     chunkOff  = (int*)alloc(NCHUNK * 4);
    int*     csr_src   = (int*)alloc((size_t)N_EDGES * 4);
    float*   deg_inv   = (float*)alloc((size_t)N_NODES * 4);
    __half2* xb        = (__half2*)alloc((size_t)N_NODES * 64 * 4);   // x fp16
    __half2* mean1     = (__half2*)alloc((size_t)N_NODES * 64 * 4);   // mean(x) fp16
    __half*  h         = (__half*)alloc((size_t)N_NODES * 256 * 2);   // layer-1 out
    __half2* pb        = (__half2*)alloc((size_t)N_NODES * 64 * 4);   // h@Wl2^T fp16
    __half*  wl1h      = (__half*)alloc(4 * 32768 * 2);
    __half*  wr1h = wl1h + 32768;
    __half*  wl2h = wr1h + 32768;
    __half*  wr2h = wl2h + 32768;

    // Fused prep: x->fp16, weights->fp16, deg=0 (one dispatch)
    prep_kernel<<<12760, 256, 0, stream>>>(x, xb, Wl1, Wr1, Wl2, Wr2,
        (__half2*)wl1h, (__half2*)wr1h, (__half2*)wl2h, (__half2*)wr2h, deg);

    // CSR build: rank-split (atomics decoupled from scatter stores)
    deg_rank_kernel<<<(N_EDGES + 255) / 256, 256, 0, stream>>>(dst, deg, rank);
    chunk_sum<<<NCHUNK, 256, 0, stream>>>(deg, partial);
    chunk_scan<<<1, 256, 0, stream>>>(partial, chunkOff);
    scatter_scan<<<NCHUNK, 256, 0, stream>>>(deg, chunkOff, row_ptr, deg_inv);
    fill_csr<<<(N_EDGES + 255) / 256, 256, 0, stream>>>(src, dst, rank, row_ptr, csr_src);

    // Layer 1: h = relu(mean(x) @ Wl1^T + x @ Wr1^T + bl1)
    gather_mean_h<<<12500, 256, 0, stream>>>(xb, row_ptr, csr_src, deg_inv, mean1);
    gemm_l1<<<GEMM_GRID, 256, 0, stream>>>(
        (const __half*)mean1, wl1h, (const __half*)xb, wr1h, bl1, h);

    // Layer 2 (reordered): p = h @ Wl2^T; out = h @ Wr2^T + bl2; out += mean(p)
    gemm_l2<<<GEMM_GRID, 256, 0, stream>>>(
        h, wl2h, wr2h, bl2, (__half*)pb, out);
    gather_mean_add_f32<<<12500, 256, 0, stream>>>(pb, row_ptr, csr_src, deg_inv, out);
}

// Round 12
// 245.109 us; speedup vs baseline: 7.1052x; 1.0552x over previous
//
#include <hip/hip_runtime.h>
#include <hip/hip_fp16.h>

#define N_NODES 50000
#define N_EDGES 800000
#define D_IN 128
#define D_HID 256
#define D_OUT 128
#define NCHUNK 196   // ceil(N_NODES / 256)
#define GEMM_GRID 512

typedef _Float16 f16x8 __attribute__((ext_vector_type(8)));
typedef float f32x4 __attribute__((ext_vector_type(4)));

// ---------------- fused prep: zero_deg + cvt x + cvt weights ------------------
// blocks [0,12500): xb; [12500,12564): 4 weight mats; [12564,12760): zero deg.

__global__ __launch_bounds__(256)
void prep_kernel(const float* __restrict__ x, __half2* __restrict__ xb,
                 const float* __restrict__ Wl1, const float* __restrict__ Wr1,
                 const float* __restrict__ Wl2, const float* __restrict__ Wr2,
                 __half2* __restrict__ wl1h, __half2* __restrict__ wr1h,
                 __half2* __restrict__ wl2h, __half2* __restrict__ wr2h,
                 int* __restrict__ deg) {
    int b = blockIdx.x;
    if (b < 12500) {
        int i = b * 256 + threadIdx.x;            // 3.2M half2
        xb[i] = __float22half2_rn(((const float2*)x)[i]);
    } else if (b < 12564) {
        int i = (b - 12500) * 256 + threadIdx.x;  // 16384 half2 per matrix
        wl1h[i] = __float22half2_rn(((const float2*)Wl1)[i]);
        wr1h[i] = __float22half2_rn(((const float2*)Wr1)[i]);
        wl2h[i] = __float22half2_rn(((const float2*)Wl2)[i]);
        wr2h[i] = __float22half2_rn(((const float2*)Wr2)[i]);
    } else {
        int i = (b - 12564) * 256 + threadIdx.x;
        if (i < N_NODES) deg[i] = 0;
    }
}

// ---------------- CSR build: rank-split (atomic pass separated from scatter) --

__global__ void deg_rank_kernel(const int* __restrict__ dst, int* __restrict__ deg,
                                int* __restrict__ rank) {
    int i = blockIdx.x * blockDim.x + threadIdx.x;
    if (i < N_EDGES) rank[i] = atomicAdd(&deg[dst[i]], 1);
}

__global__ void chunk_sum(const int* __restrict__ deg, int* __restrict__ partial) {
    __shared__ int s[256];
    int i = blockIdx.x * 256 + threadIdx.x;
    s[threadIdx.x] = (i < N_NODES) ? deg[i] : 0;
    __syncthreads();
    for (int off = 128; off > 0; off >>= 1) {
        if (threadIdx.x < off) s[threadIdx.x] += s[threadIdx.x + off];
        __syncthreads();
    }
    if (threadIdx.x == 0) partial[blockIdx.x] = s[0];
}

// Per-chunk scan with integrated cross-chunk base (chunk_scan merged in).
__global__ void scatter_scan(const int* __restrict__ deg, const int* __restrict__ partial,
                             int* __restrict__ row_ptr, float* __restrict__ deg_inv) {
    __shared__ int s[256];
    __shared__ int base_s;
    const int tid = threadIdx.x;
    const int bid = blockIdx.x;
    // base = sum partial[0..bid)   (NCHUNK = 196 < 256)
    s[tid] = (tid < bid) ? partial[tid] : 0;
    __syncthreads();
    for (int off = 128; off > 0; off >>= 1) {
        if (tid < off) s[tid] += s[tid + off];
        __syncthreads();
    }
    if (tid == 0) base_s = s[0];
    __syncthreads();
    // per-chunk inclusive scan (Hillis-Steele)
    int i = bid * 256 + tid;
    int v = (i < N_NODES) ? deg[i] : 0;
    s[tid] = v;
    __syncthreads();
    for (int off = 1; off < 256; off <<= 1) {
        int t = (tid >= off) ? s[tid - off] : 0;
        __syncthreads();
        s[tid] += t;
        __syncthreads();
    }
    if (i < N_NODES) {
        int rp = base_s + s[tid] - v;   // exclusive scan value
        row_ptr[i] = rp;
        deg_inv[i] = 1.0f / fmaxf((float)v, 1.0f);
        if (i == N_NODES - 1) row_ptr[N_NODES] = N_EDGES;
    }
}

// Atomic-free scatter: position = row_ptr[dst] + rank. Fire-and-forget stores.
__global__ void fill_csr(const int* __restrict__ src, const int* __restrict__ dst,
                         const int* __restrict__ rank, const int* __restrict__ row_ptr,
                         int* __restrict__ csr_src) {
    int e = blockIdx.x * blockDim.x + threadIdx.x;
    if (e < N_EDGES) {
        csr_src[row_ptr[dst[e]] + rank[e]] = src[e];
    }
}

// ---------------- mean aggregation: 4 edges/instruction, ILP-4 ----------------

__device__ __forceinline__ float4 load_row4(const float4* __restrict__ feat4,
                                            int src, int s) {
    return feat4[(size_t)src * 16 + s];
}

__device__ __forceinline__ void add_row(const float4& v, float (&acc)[8]) {
    const __half2* hp = (const __half2*)&v;
    float2 f0 = __half22float2(hp[0]);
    float2 f1 = __half22float2(hp[1]);
    float2 f2 = __half22float2(hp[2]);
    float2 f3 = __half22float2(hp[3]);
    acc[0] += f0.x; acc[1] += f0.y;
    acc[2] += f1.x; acc[3] += f1.y;
    acc[4] += f2.x; acc[5] += f2.y;
    acc[6] += f3.x; acc[7] += f3.y;
}

template<bool ACCUM_F32>
__device__ __forceinline__ void gather_core(const __half2* __restrict__ feat,
                                            const int* __restrict__ row_ptr,
                                            const int* __restrict__ csr_src,
                                            const float* __restrict__ deg_inv,
                                            __half2* __restrict__ outh,
                                            float* __restrict__ outf) {
    const float4* feat4 = (const float4*)feat;
    const int lane = threadIdx.x & 63;
    const int g = lane >> 4;          // edge slot 0..3
    const int s = lane & 15;          // 16B chunk within row
    const int n = blockIdx.x * 4 + (threadIdx.x >> 6);
    const int beg = row_ptr[n];
    const int end = row_ptr[n + 1];
    float acc[8] = {};
    int e = beg;
    for (; e + 16 <= end; e += 16) {  // 4 independent 4-row loads in flight
        int s0 = csr_src[e + g];
        int s1 = csr_src[e + 4 + g];
        int s2 = csr_src[e + 8 + g];
        int s3 = csr_src[e + 12 + g];
        float4 v0 = load_row4(feat4, s0, s);
        float4 v1 = load_row4(feat4, s1, s);
        float4 v2 = load_row4(feat4, s2, s);
        float4 v3 = load_row4(feat4, s3, s);
        add_row(v0, acc);
        add_row(v1, acc);
        add_row(v2, acc);
        add_row(v3, acc);
    }
    for (; e + 4 <= end; e += 4) {
        int s0 = csr_src[e + g];
        float4 v0 = load_row4(feat4, s0, s);
        add_row(v0, acc);
    }
    if (e < end) {                    // masked tail (1..3 edges)
        if (g < end - e) {
            int s0 = csr_src[e + g];
            float4 v0 = load_row4(feat4, s0, s);
            add_row(v0, acc);
        }
    }
    #pragma unroll
    for (int j = 0; j < 8; ++j) {
        acc[j] += __shfl_xor(acc[j], 16);
        acc[j] += __shfl_xor(acc[j], 32);
    }
    if (g == 0) {
        float di = deg_inv[n];
        if (ACCUM_F32) {
            float4* orow = (float4*)(outf + (size_t)n * 128);
            float4 o0 = orow[s * 2];
            float4 o1 = orow[s * 2 + 1];
            o0.x += acc[0] * di; o0.y += acc[1] * di;
            o0.z += acc[2] * di; o0.w += acc[3] * di;
            o1.x += acc[4] * di; o1.y += acc[5] * di;
            o1.z += acc[6] * di; o1.w += acc[7] * di;
            orow[s * 2] = o0;
            orow[s * 2 + 1] = o1;
        } else {
            float4 o;
            __half2* op = (__half2*)&o;
            op[0] = __float22half2_rn(make_float2(acc[0] * di, acc[1] * di));
            op[1] = __float22half2_rn(make_float2(acc[2] * di, acc[3] * di));
            op[2] = __float22half2_rn(make_float2(acc[4] * di, acc[5] * di));
            op[3] = __float22half2_rn(make_float2(acc[6] * di, acc[7] * di));
            ((float4*)(outh + (size_t)n * 64))[s] = o;
        }
    }
}

__global__ __launch_bounds__(256)
void gather_mean_h(const __half2* __restrict__ feat, const int* __restrict__ row_ptr,
                   const int* __restrict__ csr_src, const float* __restrict__ deg_inv,
                   __half2* __restrict__ outv) {
    gather_core<false>(feat, row_ptr, csr_src, deg_inv, outv, nullptr);
}

__global__ __launch_bounds__(256)
void gather_mean_add_f32(const __half2* __restrict__ feat, const int* __restrict__ row_ptr,
                         const int* __restrict__ csr_src, const float* __restrict__ deg_inv,
                         float* __restrict__ out) {
    gather_core<true>(feat, row_ptr, csr_src, deg_inv, nullptr, out);
}

// ---------------- fused MFMA GEMM: layer1 -> LDS h-tile -> layer2 -------------
// mfma_f32_16x16x32_f16 layouts (verified R4..R11):
//   A frag: lane holds A[m = lane&15][k = kc*32 + (lane>>4)*8 + j]
//   B frag: lane holds W[n = lane&15][k]  (W row-major [J,K])
//   C/D:    col = lane&15 (n), row = (lane>>4)*4 + reg
// Per 16-row tile: 4 waves compute h(16x256) = relu(mean1@Wl1^T + xb@Wr1^T + b1),
// stage fp16 into padded LDS [16][264] (double-buffered), barrier, then each
// wave computes its 32-col slices of P = h@Wl2^T and OUT = h@Wr2^T + b2.
// h never touches global memory.

#define HPAD 264

__global__ __launch_bounds__(256, 1)
void gemm_fused(const __half* __restrict__ Aa, const __half* __restrict__ Ba,
                const __half* __restrict__ Ab, const __half* __restrict__ Bb,
                const float* __restrict__ bias1,
                const __half* __restrict__ B20, const __half* __restrict__ B21,
                const float* __restrict__ bias2,
                __half* __restrict__ P, float* __restrict__ out) {
    __shared__ __half hlds[2][16][HPAD];
    const int lane = threadIdx.x & 63;
    const int wave = threadIdx.x >> 6;
    const int quad = lane >> 4;
    const int l16 = lane & 15;
    const int koff = quad * 8;

    // Layer-1 B fragments: bf1[pass][kc][nt]  (wave owns h cols wave*64..+64)
    f16x8 bf1[2][4][4];
    #pragma unroll
    for (int p = 0; p < 2; ++p) {
        const __half* __restrict__ B = p ? Bb : Ba;
        #pragma unroll
        for (int kc = 0; kc < 4; ++kc)
            #pragma unroll
            for (int nt = 0; nt < 4; ++nt)
                bf1[p][kc][nt] = *(const f16x8*)(
                    B + (size_t)(wave * 64 + nt * 16 + l16) * D_IN + kc * 32 + koff);
    }
    float bv1[4];
    #pragma unroll
    for (int nt = 0; nt < 4; ++nt) bv1[nt] = bias1[wave * 64 + nt * 16 + l16];

    // Layer-2 B fragments: bf20/bf21[kc][nt]  (wave owns P/OUT cols wave*32..+32)
    f16x8 bf20[8][2], bf21[8][2];
    #pragma unroll
    for (int kc = 0; kc < 8; ++kc)
        #pragma unroll
        for (int nt = 0; nt < 2; ++nt) {
            size_t brow = (size_t)(wave * 32 + nt * 16 + l16) * D_HID + kc * 32 + koff;
            bf20[kc][nt] = *(const f16x8*)(B20 + brow);
            bf21[kc][nt] = *(const f16x8*)(B21 + brow);
        }
    float bv2[2];
    #pragma unroll
    for (int nt = 0; nt < 2; ++nt) bv2[nt] = bias2[wave * 32 + nt * 16 + l16];

    const int NT = N_NODES / 16;            // 3125 exact
    const int g = gridDim.x;

    auto loadA = [&](int t, f16x8 (&a)[2][4]) {
        const size_t arow = (size_t)(t * 16 + l16) * D_IN + koff;
        #pragma unroll
        for (int kc = 0; kc < 4; ++kc) {
            a[0][kc] = *(const f16x8*)(Aa + arow + kc * 32);
            a[1][kc] = *(const f16x8*)(Ab + arow + kc * 32);
        }
    };

    auto step = [&](int tile, const f16x8 (&a)[2][4], int buf) {
        // ---- layer 1 ----
        f32x4 acc1[4] = {};
        #pragma unroll
        for (int p = 0; p < 2; ++p)
            #pragma unroll
            for (int kc = 0; kc < 4; ++kc)
                #pragma unroll
                for (int nt = 0; nt < 4; ++nt)
                    acc1[nt] = __builtin_amdgcn_mfma_f32_16x16x32_f16(
                        a[p][kc], bf1[p][kc][nt], acc1[nt], 0, 0, 0);
        // stage h tile (fp16, relu+bias) into LDS
        #pragma unroll
        for (int nt = 0; nt < 4; ++nt) {
            int col = wave * 64 + nt * 16 + l16;
            #pragma unroll
            for (int r = 0; r < 4; ++r)
                hlds[buf][quad * 4 + r][col] =
                    __float2half(fmaxf(acc1[nt][r] + bv1[nt], 0.f));
        }
        __syncthreads();
        // ---- layer 2 (A from LDS) ----
        f32x4 acc20[2] = {};
        f32x4 acc21[2] = {};
        #pragma unroll
        for (int kc = 0; kc < 8; ++kc) {
            f16x8 a2 = *(const f16x8*)&hlds[buf][l16][kc * 32 + koff];
            #pragma unroll
            for (int nt = 0; nt < 2; ++nt) {
                acc20[nt] = __builtin_amdgcn_mfma_f32_16x16x32_f16(
                    a2, bf20[kc][nt], acc20[nt], 0, 0, 0);
                acc21[nt] = __builtin_amdgcn_mfma_f32_16x16x32_f16(
                    a2, bf21[kc][nt], acc21[nt], 0, 0, 0);
            }
        }
        #pragma unroll
        for (int nt = 0; nt < 2; ++nt) {
            int col = wave * 32 + nt * 16 + l16;
            #pragma unroll
            for (int r = 0; r < 4; ++r) {
                int row = tile * 16 + quad * 4 + r;
                P[(size_t)row * D_OUT + col] = __float2half(acc20[nt][r]);
                out[(size_t)row * D_OUT + col] = acc21[nt][r] + bv2[nt];
            }
        }
    };

    f16x8 A0[2][4], A1[2][4];
    int tile = blockIdx.x;
    int buf = 0;
    loadA(tile, A0);
    while (true) {
        if (tile + g < NT) loadA(tile + g, A1);
        step(tile, A0, buf);
        buf ^= 1;
        tile += g;
        if (tile >= NT) break;
        if (tile + g < NT) loadA(tile + g, A0);
        step(tile, A1, buf);
        buf ^= 1;
        tile += g;
        if (tile >= NT) break;
    }
}

extern "C" void kernel_launch(void* const* d_in, const int* in_sizes, int n_in,
                              void* d_out, int out_size, void* d_ws, size_t ws_size,
                              hipStream_t stream) {
    const float* x   = (const float*)d_in[0];
    const float* Wl1 = (const float*)d_in[1];
    const float* bl1 = (const float*)d_in[2];
    const float* Wr1 = (const float*)d_in[3];
    const float* Wl2 = (const float*)d_in[4];
    const float* bl2 = (const float*)d_in[5];
    const float* Wr2 = (const float*)d_in[6];
    const int*   ei  = (const int*)d_in[7];
    const int* src = ei;              // edge_index[0]
    const int* dst = ei + N_EDGES;    // edge_index[1]
    float* out = (float*)d_out;

    // Workspace layout, 256B-aligned slabs (~46 MB)
    char* w = (char*)d_ws;
    auto alloc = [&](size_t bytes) {
        char* r = w;
        w += (bytes + 255) & ~(size_t)255;
        return r;
    };
    int*     deg       = (int*)alloc((size_t)N_NODES * 4);
    int*     row_ptr   = (int*)alloc((size_t)(N_NODES + 1) * 4);
    int*     rank      = (int*)alloc((size_t)N_EDGES * 4);
    int*     partial   = (int*)alloc(NCHUNK * 4);
    int*     csr_src   = (int*)alloc((size_t)N_EDGES * 4);
    float*   deg_inv   = (float*)alloc((size_t)N_NODES * 4);
    __half2* xb        = (__half2*)alloc((size_t)N_NODES * 64 * 4);   // x fp16
    __half2* mean1     = (__half2*)alloc((size_t)N_NODES * 64 * 4);   // mean(x) fp16
    __half2* pb        = (__half2*)alloc((size_t)N_NODES * 64 * 4);   // h@Wl2^T fp16
    __half*  wl1h      = (__half*)alloc(4 * 32768 * 2);
    __half*  wr1h = wl1h + 32768;
    __half*  wl2h = wr1h + 32768;
    __half*  wr2h = wl2h + 32768;

    // Fused prep: x->fp16, weights->fp16, deg=0 (one dispatch)
    prep_kernel<<<12760, 256, 0, stream>>>(x, xb, Wl1, Wr1, Wl2, Wr2,
        (__half2*)wl1h, (__half2*)wr1h, (__half2*)wl2h, (__half2*)wr2h, deg);

    // CSR build: rank-split (atomics decoupled from scatter stores)
    deg_rank_kernel<<<(N_EDGES + 255) / 256, 256, 0, stream>>>(dst, deg, rank);
    chunk_sum<<<NCHUNK, 256, 0, stream>>>(deg, partial);
    scatter_scan<<<NCHUNK, 256, 0, stream>>>(deg, partial, row_ptr, deg_inv);
    fill_csr<<<(N_EDGES + 255) / 256, 256, 0, stream>>>(src, dst, rank, row_ptr, csr_src);

    // Layer 1 aggregation
    gather_mean_h<<<12500, 256, 0, stream>>>(xb, row_ptr, csr_src, deg_inv, mean1);

    // Fused GEMMs: h in LDS; p = h@Wl2^T; out = h@Wr2^T + bl2
    gemm_fused<<<GEMM_GRID, 256, 0, stream>>>(
        (const __half*)mean1, wl1h, (const __half*)xb, wr1h, bl1,
        wl2h, wr2h, bl2, (__half*)pb, out);

    // out += mean(p)
    gather_mean_add_f32<<<12500, 256, 0, stream>>>(pb, row_ptr, csr_src, deg_inv, out);
}